// Round 6
// baseline (402.059 us; speedup 1.0000x reference)
//
#include <hip/hip_runtime.h>
#include <hip/hip_bf16.h>

#define OUT_STRIDE 384
#define EPSV 1e-9f
#define BSH 10
#define BS 1024            // nodes per bucket
#define NBMAX 512
#define CH 2048            // edges per multisplit chunk

typedef __attribute__((ext_vector_type(8))) short bf16x8;
typedef __attribute__((ext_vector_type(4))) float f32x4;

static __device__ __forceinline__ unsigned short f2bf(float f) {
    __hip_bfloat16 h = __float2bfloat16(f);
    return *reinterpret_cast<unsigned short*>(&h);
}

// ---------------- pass 1: bucket histogram ----------------
__global__ __launch_bounds__(256)
void bhist_kernel(const int* __restrict__ dst, int* __restrict__ bcnt, int E, int NB) {
    __shared__ int h[NBMAX];
    for (int i = threadIdx.x; i < NBMAX; i += 256) h[i] = 0;
    __syncthreads();
    int i = blockIdx.x * blockDim.x + threadIdx.x;
    int stride = gridDim.x * blockDim.x;
    for (; i < E; i += stride) atomicAdd(&h[dst[i] >> BSH], 1);
    __syncthreads();
    for (int j = threadIdx.x; j < NB; j += 256)
        if (h[j]) atomicAdd(&bcnt[j], h[j]);
}

// ---------------- pass 2: bucket scan (1 WG) ----------------
__global__ __launch_bounds__(256)
void bscan_kernel(const int* __restrict__ bcnt, int* __restrict__ bbase,
                  int* __restrict__ bcur, int* __restrict__ off,
                  int NB, int N, int E) {
    const int t = threadIdx.x;
    const int lane = t & 63, wv = t >> 6;
    int b0 = 2 * t, b1 = 2 * t + 1;
    int c0 = (b0 < NB) ? bcnt[b0] : 0;
    int c1 = (b1 < NB) ? bcnt[b1] : 0;
    int s = c0 + c1;
    int inc = s;
    #pragma unroll
    for (int d = 1; d < 64; d <<= 1) { int u = __shfl_up(inc, d); if (lane >= d) inc += u; }
    __shared__ int wt[4];
    if (lane == 63) wt[wv] = inc;
    __syncthreads();
    int base = 0;
    for (int w2 = 0; w2 < wv; ++w2) base += wt[w2];
    int ex = base + inc - s;
    if (b0 < NB) { bbase[b0] = ex;      bcur[b0] = ex; }
    if (b1 < NB) { bbase[b1] = ex + c0; bcur[b1] = ex + c0; }
    if (t == 0) { bbase[NB] = E; off[N] = E; }
}

// ---------------- pass 3: LDS-staged multisplit ----------------
__global__ __launch_bounds__(256)
void multisplit_kernel(const int* __restrict__ src, const int* __restrict__ dst,
                       const float* __restrict__ w, int* __restrict__ bcur,
                       int* __restrict__ rec, int E) {
    __shared__ int hist[NBMAX], scan_[NBMAX], gbase[NBMAX], lcur[NBMAX];
    __shared__ int recS[CH * 3];
    __shared__ int wt[4];
    const int t = threadIdx.x;
    const int lane = t & 63, wv = t >> 6;
    const int c0 = blockIdx.x * CH;
    const int cnt_total = min(CH, E - c0);

    for (int i = t; i < NBMAX; i += 256) hist[i] = 0;
    __syncthreads();
    #pragma unroll
    for (int p = 0; p < CH / 256; ++p) {
        int i = c0 + p * 256 + t;
        if (i < E) atomicAdd(&hist[dst[i] >> BSH], 1);
    }
    __syncthreads();
    {
        int b0 = 2 * t, b1 = 2 * t + 1;
        int h0 = hist[b0], h1 = hist[b1];
        int s = h0 + h1;
        int inc = s;
        #pragma unroll
        for (int d = 1; d < 64; d <<= 1) { int u = __shfl_up(inc, d); if (lane >= d) inc += u; }
        if (lane == 63) wt[wv] = inc;
        __syncthreads();
        int base = 0;
        for (int w2 = 0; w2 < wv; ++w2) base += wt[w2];
        int ex = base + inc - s;
        scan_[b0] = ex;
        scan_[b1] = ex + h0;
    }
    __syncthreads();
    for (int i = t; i < NBMAX; i += 256) {
        if (hist[i] > 0) gbase[i] = atomicAdd(&bcur[i], hist[i]);
        lcur[i] = scan_[i];
    }
    __syncthreads();
    #pragma unroll
    for (int p = 0; p < CH / 256; ++p) {
        int i = c0 + p * 256 + t;
        if (i < E) {
            int d = dst[i];
            int b = d >> BSH;
            int j = atomicAdd(&lcur[b], 1);
            recS[3 * j]     = src[i];
            recS[3 * j + 1] = d;
            recS[3 * j + 2] = __float_as_int(w[i]);
        }
    }
    __syncthreads();
    #pragma unroll
    for (int p = 0; p < CH / 256; ++p) {
        int j = p * 256 + t;
        if (j < cnt_total) {
            int d = recS[3 * j + 1];
            int b = d >> BSH;
            int g = gbase[b] + (j - scan_[b]);
            rec[3 * g]     = recS[3 * j];
            rec[3 * g + 1] = d;
            rec[3 * g + 2] = recS[3 * j + 2];
        }
    }
}

// ---------------- pass 4: per-bucket CSR build (LDS cursors) ----------------
__global__ __launch_bounds__(256)
void bucket_csr_kernel(const int* __restrict__ rec, const int* __restrict__ bbase,
                       int* __restrict__ off, int2* __restrict__ ed, int N) {
    __shared__ int h[BS];
    __shared__ int wt[4];
    const int b = blockIdx.x;
    const int t = threadIdx.x;
    const int lane = t & 63, wv = t >> 6;
    const int e0 = bbase[b], e1 = bbase[b + 1];
    const int n0 = b << BSH;
    const int nn = min(BS, N - n0);

    for (int i = t; i < BS; i += 256) h[i] = 0;
    __syncthreads();
    for (int i = e0 + t; i < e1; i += 256) atomicAdd(&h[rec[3 * i + 1] - n0], 1);
    __syncthreads();
    {
        int j0 = 4 * t;
        int l0 = h[j0], l1 = h[j0 + 1], l2 = h[j0 + 2], l3 = h[j0 + 3];
        int s = l0 + l1 + l2 + l3;
        int inc = s;
        #pragma unroll
        for (int d = 1; d < 64; d <<= 1) { int u = __shfl_up(inc, d); if (lane >= d) inc += u; }
        if (lane == 63) wt[wv] = inc;
        __syncthreads();
        int base = 0;
        for (int w2 = 0; w2 < wv; ++w2) base += wt[w2];
        int ex = base + inc - s;
        int e_[4] = {ex, ex + l0, ex + l0 + l1, ex + l0 + l1 + l2};
        __syncthreads();
        #pragma unroll
        for (int k = 0; k < 4; ++k) {
            h[j0 + k] = e_[k];
            if (j0 + k < nn) off[n0 + j0 + k] = e0 + e_[k];
        }
    }
    __syncthreads();
    for (int i = e0 + t; i < e1; i += 256) {
        int d = rec[3 * i + 1] - n0;
        int pos = atomicAdd(&h[d], 1);
        ed[e0 + pos] = make_int2(rec[3 * i], rec[3 * i + 2]);
    }
}

// ---------------- shared MFMA + LN epilogue pieces ----------------
#define XS 136

__device__ __forceinline__ void stage_W(const float* __restrict__ Wf_hop, short* Wl, int tid) {
    const float4* W4 = (const float4*)Wf_hop;
    for (int idx = tid; idx < 128 * 32; idx += 256) {
        float4 v = W4[idx];
        int row = idx >> 5;
        int col = (idx & 31) * 4;
        short* p = &Wl[row * XS + col];
        p[0] = f2bf(v.x); p[1] = f2bf(v.y); p[2] = f2bf(v.z); p[3] = f2bf(v.w);
    }
}

__device__ __forceinline__ void mfma_ln_epilogue(
    const short* Xl, const short* Wl,
    const float* __restrict__ bp, const float* __restrict__ sp, const float* __restrict__ op,
    float* out, int ocol, int n0, int N, int tid)
{
    const int lane = tid & 63;
    const int wv = tid >> 6;
    f32x4 acc[8];
    #pragma unroll
    for (int c = 0; c < 8; ++c) acc[c] = (f32x4){0.f, 0.f, 0.f, 0.f};
    const int rsub = lane & 15;
    const int g = lane >> 4;
    const short* xbase = &Xl[(wv * 16 + rsub) * XS + g * 8];
    const short* wbase = &Wl[rsub * XS + g * 8];
    #pragma unroll
    for (int kk = 0; kk < 4; ++kk) {
        bf16x8 a = *(const bf16x8*)(xbase + kk * 32);
        #pragma unroll
        for (int c = 0; c < 8; ++c) {
            bf16x8 bb = *(const bf16x8*)(wbase + c * 16 * XS + kk * 32);
            acc[c] = __builtin_amdgcn_mfma_f32_16x16x32_bf16(a, bb, acc[c], 0, 0, 0);
        }
    }
    float sum[4] = {0.f, 0.f, 0.f, 0.f};
    float ssq[4] = {0.f, 0.f, 0.f, 0.f};
    #pragma unroll
    for (int c = 0; c < 8; ++c) {
        float bias = bp[c * 16 + rsub];
        #pragma unroll
        for (int r = 0; r < 4; ++r) {
            float h = acc[c][r] + bias;
            h = fmaxf(h, 0.0f);
            acc[c][r] = h;
            sum[r] += h;
            ssq[r] += h * h;
        }
    }
    #pragma unroll
    for (int msk = 1; msk < 16; msk <<= 1) {
        #pragma unroll
        for (int r = 0; r < 4; ++r) {
            sum[r] += __shfl_xor(sum[r], msk);
            ssq[r] += __shfl_xor(ssq[r], msk);
        }
    }
    #pragma unroll
    for (int r = 0; r < 4; ++r) {
        int n = n0 + wv * 16 + g * 4 + r;
        if (n >= N) continue;
        float mean = sum[r] * (1.0f / 128.0f);
        float var = ssq[r] * (1.0f / 128.0f) - mean * mean + EPSV;
        float inv = rsqrtf(var);
        float* orow = out + (long)n * OUT_STRIDE + ocol;
        #pragma unroll
        for (int c = 0; c < 8; ++c) {
            int col = c * 16 + rsub;
            orow[col] = (acc[c][r] - mean) * sp[col] * inv + op[col];
        }
    }
}

// ---------------- packT: f32->bf16 pack + hop-0 transform ----------------
__global__ __launch_bounds__(256)
void packT_kernel(const float* __restrict__ features,
                  const float* __restrict__ Wf,
                  const float* __restrict__ bf, const float* __restrict__ scf,
                  const float* __restrict__ offp,
                  unsigned short* __restrict__ featb,
                  float* __restrict__ out, int N)
{
    __shared__ __attribute__((aligned(16))) short Wl[128 * XS];
    __shared__ __attribute__((aligned(16))) short Xl[64 * XS];
    const int tid = threadIdx.x;
    stage_W(Wf, Wl, tid);
    const int n0 = blockIdx.x * 64;
    for (int idx = tid; idx < 64 * 32; idx += 256) {
        int r = idx >> 5;
        int col = (idx & 31) * 4;
        int n = n0 + r;
        ushort4 o = make_ushort4(0, 0, 0, 0);
        if (n < N) {
            float4 v = *(const float4*)(features + (long)n * 128 + col);
            o.x = f2bf(v.x); o.y = f2bf(v.y); o.z = f2bf(v.z); o.w = f2bf(v.w);
            *(ushort4*)&featb[(long)n * 128 + col] = o;
        }
        *(ushort4*)&Xl[r * XS + col] = o;
    }
    __syncthreads();
    mfma_ln_epilogue(Xl, Wl, bf, scf, offp, out, 0, n0, N, tid);
}

// ---------------- gatherT: pull-aggregate 64 nodes + fused transform ----------------
__device__ __forceinline__ void acc8(float* a, int4 r, float w) {
    #pragma unroll
    for (int j = 0; j < 4; ++j) {
        int bits = (&r.x)[j];
        float f0 = __int_as_float(bits << 16);
        float f1 = __int_as_float(bits & 0xffff0000);
        a[2 * j]     += f0 * w;
        a[2 * j + 1] += f1 * w;
    }
}

__global__ __launch_bounds__(256)
void gatherT_kernel(const unsigned short* __restrict__ X,
                    const int* __restrict__ off, const int2* __restrict__ ed,
                    const float* __restrict__ Dn,
                    const float* __restrict__ Wf_hop,
                    const float* __restrict__ bp, const float* __restrict__ sp,
                    const float* __restrict__ op,
                    unsigned short* __restrict__ rowout,   // h1b or nullptr
                    float* __restrict__ out, int ocol, int N)
{
    __shared__ __attribute__((aligned(16))) short Wl[128 * XS];
    __shared__ __attribute__((aligned(16))) short Xl[64 * XS];
    const int tid = threadIdx.x;
    stage_W(Wf_hop, Wl, tid);

    const int l = tid & 15;
    const int grp = tid >> 4;          // 0..15, one 16-lane group -> 4 nodes
    const int n0 = blockIdx.x * 64;
    const unsigned short* Xc = X + 8 * l;
    #pragma unroll
    for (int q = 0; q < 4; ++q) {
        int n = n0 + grp * 4 + q;
        int r = grp * 4 + q;
        if (n < N) {
            const int beg = off[n], end = off[n + 1];
            float a[8] = {0.f, 0.f, 0.f, 0.f, 0.f, 0.f, 0.f, 0.f};
            int i = beg;
            for (; i + 3 < end; i += 4) {
                int2 e0 = ed[i], e1 = ed[i + 1], e2 = ed[i + 2], e3 = ed[i + 3];
                int4 r0 = *(const int4*)(Xc + (long)e0.x * 128);
                int4 r1 = *(const int4*)(Xc + (long)e1.x * 128);
                int4 r2 = *(const int4*)(Xc + (long)e2.x * 128);
                int4 r3 = *(const int4*)(Xc + (long)e3.x * 128);
                acc8(a, r0, __int_as_float(e0.y));
                acc8(a, r1, __int_as_float(e1.y));
                acc8(a, r2, __int_as_float(e2.y));
                acc8(a, r3, __int_as_float(e3.y));
            }
            for (; i < end; ++i) {
                int2 e0 = ed[i];
                int4 r0 = *(const int4*)(Xc + (long)e0.x * 128);
                acc8(a, r0, __int_as_float(e0.y));
            }
            const float dn = Dn[n];
            int4 o;
            #pragma unroll
            for (int j = 0; j < 4; ++j) {
                unsigned lo = f2bf(a[2 * j] * dn);
                unsigned hi = f2bf(a[2 * j + 1] * dn);
                (&o.x)[j] = (int)((hi << 16) | lo);
            }
            *(int4*)&Xl[r * XS + 8 * l] = o;
            if (rowout) *(int4*)&rowout[(long)n * 128 + 8 * l] = o;
        } else {
            int4 z = make_int4(0, 0, 0, 0);
            *(int4*)&Xl[r * XS + 8 * l] = z;
        }
    }
    __syncthreads();
    mfma_ln_epilogue(Xl, Wl, bp, sp, op, out, ocol, n0, N, tid);
}

// ---------------- fallback: push scatter + generic transform ----------------
__global__ __launch_bounds__(256)
void scatter_kernel(const float* X, long xstride, long xcol0,
                    const int* __restrict__ src, const int* __restrict__ dst,
                    const float* __restrict__ w, const float* __restrict__ Dn,
                    int useDn, float* out, long ocol0, int nE)
{
    const int lane = threadIdx.x & 63;
    const int wave = (int)((blockIdx.x * blockDim.x + threadIdx.x) >> 6);
    const int nWaves = (int)((gridDim.x * blockDim.x) >> 6);
    for (int e = wave; e < nE; e += nWaves) {
        const int s = src[e];
        const int d = dst[e];
        float ww = w[e];
        if (useDn) ww *= Dn[s];
        const float2 v = *(const float2*)(X + (long)s * xstride + xcol0 + 2 * lane);
        float* o = out + (long)d * OUT_STRIDE + ocol0 + 2 * lane;
        atomicAdd(o, v.x * ww);
        atomicAdd(o + 1, v.y * ww);
    }
}

__global__ __launch_bounds__(256)
void transform_f32_kernel(const float* x, long xs, int useDnIn,
                          const float* __restrict__ Dn,
                          const float* __restrict__ Wf_hop,
                          const float* __restrict__ bp, const float* __restrict__ sp,
                          const float* __restrict__ op,
                          float* out, int ocol, int N)
{
    __shared__ __attribute__((aligned(16))) short Wl[128 * XS];
    __shared__ __attribute__((aligned(16))) short Xl[64 * XS];
    const int tid = threadIdx.x;
    stage_W(Wf_hop, Wl, tid);
    const int n0 = blockIdx.x * 64;
    for (int idx = tid; idx < 64 * 32; idx += 256) {
        int r = idx >> 5;
        int col = (idx & 31) * 4;
        int n = n0 + r;
        float4 v = make_float4(0.f, 0.f, 0.f, 0.f);
        float m = 1.0f;
        if (n < N) {
            v = *(const float4*)(x + (long)n * xs + col);
            if (useDnIn) m = Dn[n];
        }
        short* p = &Xl[r * XS + col];
        p[0] = f2bf(v.x * m); p[1] = f2bf(v.y * m); p[2] = f2bf(v.z * m); p[3] = f2bf(v.w * m);
    }
    __syncthreads();
    mfma_ln_epilogue(Xl, Wl, bp, sp, op, out, ocol, n0, N, tid);
}

extern "C" void kernel_launch(void* const* d_in, const int* in_sizes, int n_in,
                              void* d_out, int out_size, void* d_ws, size_t ws_size,
                              hipStream_t stream) {
    const float* features = (const float*)d_in[0];
    const int*   src      = (const int*)d_in[1];
    const int*   dst      = (const int*)d_in[2];
    const float* w        = (const float*)d_in[3];
    const float* Dn       = (const float*)d_in[4];
    const float* W        = (const float*)d_in[5];
    const float* b        = (const float*)d_in[6];
    const float* scale    = (const float*)d_in[7];
    const float* offset   = (const float*)d_in[8];
    float* out = (float*)d_out;
    const int N = in_sizes[0] / 128;
    const int E = in_sizes[1];
    const int NB = (N + BS - 1) >> BSH;

    // ws layout (ints): off[N+1] | ed[2E] | bcnt[NB] bbase[NB+1] bcur[NB] | union{rec[3E]; featb[64N] h1b[64N]}
    const size_t o_off = 0;
    const size_t o_ed  = ((size_t)N + 1 + 3) & ~(size_t)3;
    const size_t o_b   = o_ed + 2 * (size_t)E;
    const size_t o_uni = (o_b + 3 * (size_t)NB + 1 + 3) & ~(size_t)3;
    const size_t uni   = (size_t)128 * N > 3 * (size_t)E ? (size_t)128 * N : 3 * (size_t)E;
    const size_t need  = (o_uni + uni) * 4;
    const int nblk = (N + 63) / 64;

    if (NB <= NBMAX && ws_size >= need) {
        int* ws_i  = (int*)d_ws;
        int* off   = ws_i + o_off;
        int2* ed   = (int2*)(ws_i + o_ed);
        int* bcnt  = ws_i + o_b;
        int* bbase = bcnt + NB;
        int* bcur  = bbase + NB + 1;
        int* rec   = ws_i + o_uni;
        unsigned short* featb = (unsigned short*)(ws_i + o_uni);
        unsigned short* h1b   = featb + (size_t)N * 128;

        hipMemsetAsync(bcnt, 0, (size_t)NB * 4, stream);
        bhist_kernel<<<512, 256, 0, stream>>>(dst, bcnt, E, NB);
        bscan_kernel<<<1, 256, 0, stream>>>(bcnt, bbase, bcur, off, NB, N, E);
        multisplit_kernel<<<(E + CH - 1) / CH, 256, 0, stream>>>(src, dst, w, bcur, rec, E);
        bucket_csr_kernel<<<NB, 256, 0, stream>>>(rec, bbase, off, ed, N);

        // rec dead; featb/h1b reuse its space. NOTE: featb overlaps rec region,
        // so packT must run after bucket_csr (stream-ordered: yes).
        packT_kernel<<<nblk, 256, 0, stream>>>(features, W, b, scale, offset, featb, out, N);
        gatherT_kernel<<<nblk, 256, 0, stream>>>(featb, off, ed, Dn,
                W + 128 * 128, b + 128, scale + 128, offset + 128, h1b, out, 128, N);
        gatherT_kernel<<<nblk, 256, 0, stream>>>(h1b, off, ed, Dn,
                W + 2 * 128 * 128, b + 256, scale + 256, offset + 256, nullptr, out, 256, N);
    } else {
        // fallback: atomic scatter path (raw agg stored; Dn applied on read)
        hipMemsetAsync(out, 0, (size_t)out_size * sizeof(float), stream);
        scatter_kernel<<<2048, 256, 0, stream>>>(features, 128, 0, src, dst, w, Dn, 0, out, 128, E);
        scatter_kernel<<<2048, 256, 0, stream>>>(out, OUT_STRIDE, 128, src, dst, w, Dn, 1, out, 256, E);
        transform_f32_kernel<<<nblk, 256, 0, stream>>>(features, 128, 0, Dn, W, b, scale, offset, out, 0, N);
        transform_f32_kernel<<<nblk, 256, 0, stream>>>(out + 128, OUT_STRIDE, 1, Dn, W + 128 * 128, b + 128, scale + 128, offset + 128, out, 128, N);
        transform_f32_kernel<<<nblk, 256, 0, stream>>>(out + 256, OUT_STRIDE, 1, Dn, W + 2 * 128 * 128, b + 256, scale + 256, offset + 256, out, 256, N);
    }
}

// Round 7
// 380.646 us; speedup vs baseline: 1.0563x; 1.0563x over previous
//
#include <hip/hip_runtime.h>
#include <hip/hip_bf16.h>

#define OUT_STRIDE 384
#define EPSV 1e-9f
#define BSH 10
#define BS 1024            // nodes per bucket
#define NBMAX 512
#define CH 2048            // edges per multisplit chunk

typedef __attribute__((ext_vector_type(8))) short bf16x8;
typedef __attribute__((ext_vector_type(4))) float f32x4;

static __device__ __forceinline__ unsigned short f2bf(float f) {
    __hip_bfloat16 h = __float2bfloat16(f);
    return *reinterpret_cast<unsigned short*>(&h);
}

// ---------------- pass 1: bucket histogram ----------------
__global__ __launch_bounds__(256)
void bhist_kernel(const int* __restrict__ dst, int* __restrict__ bcnt, int E, int NB) {
    __shared__ int h[NBMAX];
    for (int i = threadIdx.x; i < NBMAX; i += 256) h[i] = 0;
    __syncthreads();
    int i = blockIdx.x * blockDim.x + threadIdx.x;
    int stride = gridDim.x * blockDim.x;
    for (; i < E; i += stride) atomicAdd(&h[dst[i] >> BSH], 1);
    __syncthreads();
    for (int j = threadIdx.x; j < NB; j += 256)
        if (h[j]) atomicAdd(&bcnt[j], h[j]);
}

// ---------------- pass 2: bucket scan (1 WG) ----------------
__global__ __launch_bounds__(256)
void bscan_kernel(const int* __restrict__ bcnt, int* __restrict__ bbase,
                  int* __restrict__ bcur, int* __restrict__ off,
                  int NB, int N, int E) {
    const int t = threadIdx.x;
    const int lane = t & 63, wv = t >> 6;
    int b0 = 2 * t, b1 = 2 * t + 1;
    int c0 = (b0 < NB) ? bcnt[b0] : 0;
    int c1 = (b1 < NB) ? bcnt[b1] : 0;
    int s = c0 + c1;
    int inc = s;
    #pragma unroll
    for (int d = 1; d < 64; d <<= 1) { int u = __shfl_up(inc, d); if (lane >= d) inc += u; }
    __shared__ int wt[4];
    if (lane == 63) wt[wv] = inc;
    __syncthreads();
    int base = 0;
    for (int w2 = 0; w2 < wv; ++w2) base += wt[w2];
    int ex = base + inc - s;
    if (b0 < NB) { bbase[b0] = ex;      bcur[b0] = ex; }
    if (b1 < NB) { bbase[b1] = ex + c0; bcur[b1] = ex + c0; }
    if (t == 0) { bbase[NB] = E; off[N] = E; }
}

// ---------------- pass 3: LDS-staged multisplit ----------------
__global__ __launch_bounds__(256)
void multisplit_kernel(const int* __restrict__ src, const int* __restrict__ dst,
                       const float* __restrict__ w, int* __restrict__ bcur,
                       int* __restrict__ rec, int E) {
    __shared__ int hist[NBMAX], scan_[NBMAX], gbase[NBMAX], lcur[NBMAX];
    __shared__ int recS[CH * 3];
    __shared__ int wt[4];
    const int t = threadIdx.x;
    const int lane = t & 63, wv = t >> 6;
    const int c0 = blockIdx.x * CH;
    const int cnt_total = min(CH, E - c0);

    for (int i = t; i < NBMAX; i += 256) hist[i] = 0;
    __syncthreads();
    #pragma unroll
    for (int p = 0; p < CH / 256; ++p) {
        int i = c0 + p * 256 + t;
        if (i < E) atomicAdd(&hist[dst[i] >> BSH], 1);
    }
    __syncthreads();
    {
        int b0 = 2 * t, b1 = 2 * t + 1;
        int h0 = hist[b0], h1 = hist[b1];
        int s = h0 + h1;
        int inc = s;
        #pragma unroll
        for (int d = 1; d < 64; d <<= 1) { int u = __shfl_up(inc, d); if (lane >= d) inc += u; }
        if (lane == 63) wt[wv] = inc;
        __syncthreads();
        int base = 0;
        for (int w2 = 0; w2 < wv; ++w2) base += wt[w2];
        int ex = base + inc - s;
        scan_[b0] = ex;
        scan_[b1] = ex + h0;
    }
    __syncthreads();
    for (int i = t; i < NBMAX; i += 256) {
        if (hist[i] > 0) gbase[i] = atomicAdd(&bcur[i], hist[i]);
        lcur[i] = scan_[i];
    }
    __syncthreads();
    #pragma unroll
    for (int p = 0; p < CH / 256; ++p) {
        int i = c0 + p * 256 + t;
        if (i < E) {
            int d = dst[i];
            int b = d >> BSH;
            int j = atomicAdd(&lcur[b], 1);
            recS[3 * j]     = src[i];
            recS[3 * j + 1] = d;
            recS[3 * j + 2] = __float_as_int(w[i]);
        }
    }
    __syncthreads();
    #pragma unroll
    for (int p = 0; p < CH / 256; ++p) {
        int j = p * 256 + t;
        if (j < cnt_total) {
            int d = recS[3 * j + 1];
            int b = d >> BSH;
            int g = gbase[b] + (j - scan_[b]);
            rec[3 * g]     = recS[3 * j];
            rec[3 * g + 1] = d;
            rec[3 * g + 2] = recS[3 * j + 2];
        }
    }
}

// ---------------- pass 4: per-bucket CSR build (LDS cursors) ----------------
__global__ __launch_bounds__(256)
void bucket_csr_kernel(const int* __restrict__ rec, const int* __restrict__ bbase,
                       int* __restrict__ off, int2* __restrict__ ed, int N) {
    __shared__ int h[BS];
    __shared__ int wt[4];
    const int b = blockIdx.x;
    const int t = threadIdx.x;
    const int lane = t & 63, wv = t >> 6;
    const int e0 = bbase[b], e1 = bbase[b + 1];
    const int n0 = b << BSH;
    const int nn = min(BS, N - n0);

    for (int i = t; i < BS; i += 256) h[i] = 0;
    __syncthreads();
    for (int i = e0 + t; i < e1; i += 256) atomicAdd(&h[rec[3 * i + 1] - n0], 1);
    __syncthreads();
    {
        int j0 = 4 * t;
        int l0 = h[j0], l1 = h[j0 + 1], l2 = h[j0 + 2], l3 = h[j0 + 3];
        int s = l0 + l1 + l2 + l3;
        int inc = s;
        #pragma unroll
        for (int d = 1; d < 64; d <<= 1) { int u = __shfl_up(inc, d); if (lane >= d) inc += u; }
        if (lane == 63) wt[wv] = inc;
        __syncthreads();
        int base = 0;
        for (int w2 = 0; w2 < wv; ++w2) base += wt[w2];
        int ex = base + inc - s;
        int e_[4] = {ex, ex + l0, ex + l0 + l1, ex + l0 + l1 + l2};
        __syncthreads();
        #pragma unroll
        for (int k = 0; k < 4; ++k) {
            h[j0 + k] = e_[k];
            if (j0 + k < nn) off[n0 + j0 + k] = e0 + e_[k];
        }
    }
    __syncthreads();
    for (int i = e0 + t; i < e1; i += 256) {
        int d = rec[3 * i + 1] - n0;
        int pos = atomicAdd(&h[d], 1);
        ed[e0 + pos] = make_int2(rec[3 * i], rec[3 * i + 2]);
    }
}

// ---------------- shared MFMA + LN epilogue ----------------
#define XS 136

__device__ __forceinline__ void stage_W(const float* __restrict__ Wf_hop, short* Wl, int tid) {
    const float4* W4 = (const float4*)Wf_hop;
    for (int idx = tid; idx < 128 * 32; idx += 256) {
        float4 v = W4[idx];
        int row = idx >> 5;
        int col = (idx & 31) * 4;
        short* p = &Wl[row * XS + col];
        p[0] = f2bf(v.x); p[1] = f2bf(v.y); p[2] = f2bf(v.z); p[3] = f2bf(v.w);
    }
}

__device__ __forceinline__ void mfma_ln_epilogue(
    const short* Xl, const short* Wl,
    const float* __restrict__ bp, const float* __restrict__ sp, const float* __restrict__ op,
    float* out, int ocol, int n0, int N, int tid)
{
    const int lane = tid & 63;
    const int wv = tid >> 6;
    f32x4 acc[8];
    #pragma unroll
    for (int c = 0; c < 8; ++c) acc[c] = (f32x4){0.f, 0.f, 0.f, 0.f};
    const int rsub = lane & 15;
    const int g = lane >> 4;
    const short* xbase = &Xl[(wv * 16 + rsub) * XS + g * 8];
    const short* wbase = &Wl[rsub * XS + g * 8];
    #pragma unroll
    for (int kk = 0; kk < 4; ++kk) {
        bf16x8 a = *(const bf16x8*)(xbase + kk * 32);
        #pragma unroll
        for (int c = 0; c < 8; ++c) {
            bf16x8 bb = *(const bf16x8*)(wbase + c * 16 * XS + kk * 32);
            acc[c] = __builtin_amdgcn_mfma_f32_16x16x32_bf16(a, bb, acc[c], 0, 0, 0);
        }
    }
    float sum[4] = {0.f, 0.f, 0.f, 0.f};
    float ssq[4] = {0.f, 0.f, 0.f, 0.f};
    #pragma unroll
    for (int c = 0; c < 8; ++c) {
        float bias = bp[c * 16 + rsub];
        #pragma unroll
        for (int r = 0; r < 4; ++r) {
            float h = acc[c][r] + bias;
            h = fmaxf(h, 0.0f);
            acc[c][r] = h;
            sum[r] += h;
            ssq[r] += h * h;
        }
    }
    #pragma unroll
    for (int msk = 1; msk < 16; msk <<= 1) {
        #pragma unroll
        for (int r = 0; r < 4; ++r) {
            sum[r] += __shfl_xor(sum[r], msk);
            ssq[r] += __shfl_xor(ssq[r], msk);
        }
    }
    #pragma unroll
    for (int r = 0; r < 4; ++r) {
        int n = n0 + wv * 16 + g * 4 + r;
        if (n >= N) continue;
        float mean = sum[r] * (1.0f / 128.0f);
        float var = ssq[r] * (1.0f / 128.0f) - mean * mean + EPSV;
        float inv = rsqrtf(var);
        float* orow = out + (long)n * OUT_STRIDE + ocol;
        #pragma unroll
        for (int c = 0; c < 8; ++c) {
            int col = c * 16 + rsub;
            orow[col] = (acc[c][r] - mean) * sp[col] * inv + op[col];
        }
    }
}

// ---------------- packT: f32->bf16 pack + hop-0 transform (streaming; occ-insensitive) ----------------
__global__ __launch_bounds__(256)
void packT_kernel(const float* __restrict__ features,
                  const float* __restrict__ Wf,
                  const float* __restrict__ bf, const float* __restrict__ scf,
                  const float* __restrict__ offp,
                  unsigned short* __restrict__ featb,
                  float* __restrict__ out, int N)
{
    __shared__ __attribute__((aligned(16))) short Wl[128 * XS];
    __shared__ __attribute__((aligned(16))) short Xl[64 * XS];
    const int tid = threadIdx.x;
    stage_W(Wf, Wl, tid);
    const int n0 = blockIdx.x * 64;
    for (int idx = tid; idx < 64 * 32; idx += 256) {
        int r = idx >> 5;
        int col = (idx & 31) * 4;
        int n = n0 + r;
        ushort4 o = make_ushort4(0, 0, 0, 0);
        if (n < N) {
            float4 v = *(const float4*)(features + (long)n * 128 + col);
            o.x = f2bf(v.x); o.y = f2bf(v.y); o.z = f2bf(v.z); o.w = f2bf(v.w);
            *(ushort4*)&featb[(long)n * 128 + col] = o;
        }
        *(ushort4*)&Xl[r * XS + col] = o;
    }
    __syncthreads();
    mfma_ln_epilogue(Xl, Wl, bf, scf, offp, out, 0, n0, N, tid);
}

// ---------------- gather: pull aggregate over bf16 rows, high-occupancy (R5 form) ----------------
__device__ __forceinline__ void acc8(float* a, int4 r, float w) {
    #pragma unroll
    for (int j = 0; j < 4; ++j) {
        int bits = (&r.x)[j];
        float f0 = __int_as_float(bits << 16);
        float f1 = __int_as_float(bits & 0xffff0000);
        a[2 * j]     += f0 * w;
        a[2 * j + 1] += f1 * w;
    }
}

__global__ __launch_bounds__(256)
void gather_bf16in(const unsigned short* __restrict__ X,
                   const int* __restrict__ off, const int2* __restrict__ ed,
                   const float* __restrict__ Dn,
                   unsigned short* __restrict__ outb, int N) {
    const int tid = threadIdx.x;
    const int l = tid & 15;
    const int n = blockIdx.x * 16 + (tid >> 4);
    if (n >= N) return;
    const int beg = off[n], end = off[n + 1];
    float a[8] = {0.f, 0.f, 0.f, 0.f, 0.f, 0.f, 0.f, 0.f};
    const unsigned short* Xc = X + 8 * l;
    int i = beg;
    for (; i + 3 < end; i += 4) {
        int2 e0 = ed[i], e1 = ed[i + 1], e2 = ed[i + 2], e3 = ed[i + 3];
        int4 r0 = *(const int4*)(Xc + (long)e0.x * 128);
        int4 r1 = *(const int4*)(Xc + (long)e1.x * 128);
        int4 r2 = *(const int4*)(Xc + (long)e2.x * 128);
        int4 r3 = *(const int4*)(Xc + (long)e3.x * 128);
        acc8(a, r0, __int_as_float(e0.y));
        acc8(a, r1, __int_as_float(e1.y));
        acc8(a, r2, __int_as_float(e2.y));
        acc8(a, r3, __int_as_float(e3.y));
    }
    for (; i < end; ++i) {
        int2 e0 = ed[i];
        int4 r0 = *(const int4*)(Xc + (long)e0.x * 128);
        acc8(a, r0, __int_as_float(e0.y));
    }
    const float dn = Dn[n];
    int4 o;
    #pragma unroll
    for (int j = 0; j < 4; ++j) {
        unsigned lo = f2bf(a[2 * j] * dn);
        unsigned hi = f2bf(a[2 * j + 1] * dn);
        (&o.x)[j] = (int)((hi << 16) | lo);
    }
    *(int4*)&outb[(long)n * 128 + 8 * l] = o;
}

// ---------------- transform for hops 1,2 from bf16 rows ----------------
__global__ __launch_bounds__(256)
void transformB_kernel(const unsigned short* __restrict__ h1b,
                       const unsigned short* __restrict__ h2b,
                       const float* __restrict__ Wf,
                       const float* __restrict__ bf, const float* __restrict__ scf,
                       const float* __restrict__ offp,
                       float* out, int N)
{
    const int hop = blockIdx.y + 1;
    const int tid = threadIdx.x;
    __shared__ __attribute__((aligned(16))) short Wl[128 * XS];
    __shared__ __attribute__((aligned(16))) short Xl[64 * XS];
    stage_W(Wf + (long)hop * 128 * 128, Wl, tid);
    const unsigned short* xb = (hop == 1) ? h1b : h2b;
    const int n0 = blockIdx.x * 64;
    for (int idx = tid; idx < 64 * 16; idx += 256) {
        int r = idx >> 4;
        int c = (idx & 15) * 8;
        int n = n0 + r;
        int4 v = make_int4(0, 0, 0, 0);
        if (n < N) v = *(const int4*)(xb + (long)n * 128 + c);
        *(int4*)&Xl[r * XS + c] = v;
    }
    __syncthreads();
    mfma_ln_epilogue(Xl, Wl, bf + hop * 128, scf + hop * 128, offp + hop * 128,
                     out, hop * 128, n0, N, tid);
}

// ---------------- fallback: push scatter + generic transform ----------------
__global__ __launch_bounds__(256)
void scatter_kernel(const float* X, long xstride, long xcol0,
                    const int* __restrict__ src, const int* __restrict__ dst,
                    const float* __restrict__ w, const float* __restrict__ Dn,
                    int useDn, float* out, long ocol0, int nE)
{
    const int lane = threadIdx.x & 63;
    const int wave = (int)((blockIdx.x * blockDim.x + threadIdx.x) >> 6);
    const int nWaves = (int)((gridDim.x * blockDim.x) >> 6);
    for (int e = wave; e < nE; e += nWaves) {
        const int s = src[e];
        const int d = dst[e];
        float ww = w[e];
        if (useDn) ww *= Dn[s];
        const float2 v = *(const float2*)(X + (long)s * xstride + xcol0 + 2 * lane);
        float* o = out + (long)d * OUT_STRIDE + ocol0 + 2 * lane;
        atomicAdd(o, v.x * ww);
        atomicAdd(o + 1, v.y * ww);
    }
}

__global__ __launch_bounds__(256)
void transform_f32_kernel(const float* x, long xs, int useDnIn,
                          const float* __restrict__ Dn,
                          const float* __restrict__ Wf_hop,
                          const float* __restrict__ bp, const float* __restrict__ sp,
                          const float* __restrict__ op,
                          float* out, int ocol, int N)
{
    __shared__ __attribute__((aligned(16))) short Wl[128 * XS];
    __shared__ __attribute__((aligned(16))) short Xl[64 * XS];
    const int tid = threadIdx.x;
    stage_W(Wf_hop, Wl, tid);
    const int n0 = blockIdx.x * 64;
    for (int idx = tid; idx < 64 * 32; idx += 256) {
        int r = idx >> 5;
        int col = (idx & 31) * 4;
        int n = n0 + r;
        float4 v = make_float4(0.f, 0.f, 0.f, 0.f);
        float m = 1.0f;
        if (n < N) {
            v = *(const float4*)(x + (long)n * xs + col);
            if (useDnIn) m = Dn[n];
        }
        short* p = &Xl[r * XS + col];
        p[0] = f2bf(v.x * m); p[1] = f2bf(v.y * m); p[2] = f2bf(v.z * m); p[3] = f2bf(v.w * m);
    }
    __syncthreads();
    mfma_ln_epilogue(Xl, Wl, bp, sp, op, out, ocol, n0, N, tid);
}

extern "C" void kernel_launch(void* const* d_in, const int* in_sizes, int n_in,
                              void* d_out, int out_size, void* d_ws, size_t ws_size,
                              hipStream_t stream) {
    const float* features = (const float*)d_in[0];
    const int*   src      = (const int*)d_in[1];
    const int*   dst      = (const int*)d_in[2];
    const float* w        = (const float*)d_in[3];
    const float* Dn       = (const float*)d_in[4];
    const float* W        = (const float*)d_in[5];
    const float* b        = (const float*)d_in[6];
    const float* scale    = (const float*)d_in[7];
    const float* offset   = (const float*)d_in[8];
    float* out = (float*)d_out;
    const int N = in_sizes[0] / 128;
    const int E = in_sizes[1];
    const int NB = (N + BS - 1) >> BSH;
    const int nblk = (N + 63) / 64;

    // ws layout (ints), no aliasing:
    // off[N+1] | ed[2E] | bcnt[NB] bbase[NB+1] bcur[NB] | rec[3E] | featb[64N] | h1b[64N] | h2b[64N]
    const size_t o_off = 0;
    const size_t o_ed  = ((size_t)N + 1 + 3) & ~(size_t)3;
    const size_t o_b   = o_ed + 2 * (size_t)E;
    const size_t o_rec = (o_b + 3 * (size_t)NB + 1 + 3) & ~(size_t)3;
    const size_t o_fb  = o_rec + 3 * (size_t)E;
    const size_t need  = (o_fb + 3 * (size_t)64 * N) * 4;

    if (NB <= NBMAX && ws_size >= need) {
        int* ws_i  = (int*)d_ws;
        int* off   = ws_i + o_off;
        int2* ed   = (int2*)(ws_i + o_ed);
        int* bcnt  = ws_i + o_b;
        int* bbase = bcnt + NB;
        int* bcur  = bbase + NB + 1;
        int* rec   = ws_i + o_rec;
        unsigned short* featb = (unsigned short*)(ws_i + o_fb);
        unsigned short* h1b   = featb + (size_t)N * 128;
        unsigned short* h2b   = h1b + (size_t)N * 128;

        hipMemsetAsync(bcnt, 0, (size_t)NB * 4, stream);
        bhist_kernel<<<512, 256, 0, stream>>>(dst, bcnt, E, NB);
        bscan_kernel<<<1, 256, 0, stream>>>(bcnt, bbase, bcur, off, NB, N, E);
        multisplit_kernel<<<(E + CH - 1) / CH, 256, 0, stream>>>(src, dst, w, bcur, rec, E);
        bucket_csr_kernel<<<NB, 256, 0, stream>>>(rec, bbase, off, ed, N);

        packT_kernel<<<nblk, 256, 0, stream>>>(features, W, b, scale, offset, featb, out, N);
        gather_bf16in<<<(N + 15) / 16, 256, 0, stream>>>(featb, off, ed, Dn, h1b, N);
        gather_bf16in<<<(N + 15) / 16, 256, 0, stream>>>(h1b, off, ed, Dn, h2b, N);

        dim3 tg(nblk, 2);
        transformB_kernel<<<tg, 256, 0, stream>>>(h1b, h2b, W, b, scale, offset, out, N);
    } else {
        // fallback: atomic scatter path (raw agg stored; Dn applied on read)
        hipMemsetAsync(out, 0, (size_t)out_size * sizeof(float), stream);
        scatter_kernel<<<2048, 256, 0, stream>>>(features, 128, 0, src, dst, w, Dn, 0, out, 128, E);
        scatter_kernel<<<2048, 256, 0, stream>>>(out, OUT_STRIDE, 128, src, dst, w, Dn, 1, out, 256, E);
        transform_f32_kernel<<<nblk, 256, 0, stream>>>(features, 128, 0, Dn, W, b, scale, offset, out, 0, N);
        transform_f32_kernel<<<nblk, 256, 0, stream>>>(out + 128, OUT_STRIDE, 1, Dn, W + 128 * 128, b + 128, scale + 128, offset + 128, out, 128, N);
        transform_f32_kernel<<<nblk, 256, 0, stream>>>(out + 256, OUT_STRIDE, 1, Dn, W + 2 * 128 * 128, b + 256, scale + 256, offset + 256, out, 256, N);
    }
}

// Round 8
// 354.087 us; speedup vs baseline: 1.1355x; 1.0750x over previous
//
#include <hip/hip_runtime.h>
#include <hip/hip_bf16.h>

#define OUT_STRIDE 384
#define EPSV 1e-9f
#define BSH 10
#define BS 1024            // nodes per bucket
#define NBMAX 512
#define CH 4096            // edges per multisplit chunk

typedef __attribute__((ext_vector_type(8))) short bf16x8;
typedef __attribute__((ext_vector_type(4))) float f32x4;

static __device__ __forceinline__ unsigned short f2bf(float f) {
    __hip_bfloat16 h = __float2bfloat16(f);
    return *reinterpret_cast<unsigned short*>(&h);
}

// ---------------- pass 1: bucket histogram + feature bf16 pack (fused streams) ----------------
__global__ __launch_bounds__(256)
void bhist_pack_kernel(const int* __restrict__ dst, int* __restrict__ bcnt, int E, int NB,
                       const float* __restrict__ features, unsigned short* __restrict__ featb,
                       long n4) {
    __shared__ int h[NBMAX];
    for (int i = threadIdx.x; i < NBMAX; i += 256) h[i] = 0;
    __syncthreads();
    int i = blockIdx.x * blockDim.x + threadIdx.x;
    int stride = gridDim.x * blockDim.x;
    for (int e = i; e < E; e += stride) atomicAdd(&h[dst[e] >> BSH], 1);
    // independent stream: pack features f32 -> bf16 (no sync needed)
    for (long p = i; p < n4; p += stride) {
        float4 v = ((const float4*)features)[p];
        ushort4 o;
        o.x = f2bf(v.x); o.y = f2bf(v.y); o.z = f2bf(v.z); o.w = f2bf(v.w);
        *(ushort4*)&featb[p * 4] = o;
    }
    __syncthreads();
    for (int j = threadIdx.x; j < NB; j += 256)
        if (h[j]) atomicAdd(&bcnt[j], h[j]);
}

// ---------------- pass 2: bucket scan (1 WG) ----------------
__global__ __launch_bounds__(256)
void bscan_kernel(const int* __restrict__ bcnt, int* __restrict__ bbase,
                  int* __restrict__ bcur, int* __restrict__ off,
                  int NB, int N, int E) {
    const int t = threadIdx.x;
    const int lane = t & 63, wv = t >> 6;
    int b0 = 2 * t, b1 = 2 * t + 1;
    int c0 = (b0 < NB) ? bcnt[b0] : 0;
    int c1 = (b1 < NB) ? bcnt[b1] : 0;
    int s = c0 + c1;
    int inc = s;
    #pragma unroll
    for (int d = 1; d < 64; d <<= 1) { int u = __shfl_up(inc, d); if (lane >= d) inc += u; }
    __shared__ int wt[4];
    if (lane == 63) wt[wv] = inc;
    __syncthreads();
    int base = 0;
    for (int w2 = 0; w2 < wv; ++w2) base += wt[w2];
    int ex = base + inc - s;
    if (b0 < NB) { bbase[b0] = ex;      bcur[b0] = ex; }
    if (b1 < NB) { bbase[b1] = ex + c0; bcur[b1] = ex + c0; }
    if (t == 0) { bbase[NB] = E; off[N] = E; }
}

// ---------------- pass 3: LDS-staged multisplit ----------------
__global__ __launch_bounds__(256)
void multisplit_kernel(const int* __restrict__ src, const int* __restrict__ dst,
                       const float* __restrict__ w, int* __restrict__ bcur,
                       int* __restrict__ rec, int E) {
    __shared__ int hist[NBMAX], scan_[NBMAX], gbase[NBMAX], lcur[NBMAX];
    __shared__ int recS[CH * 3];
    __shared__ int wt[4];
    const int t = threadIdx.x;
    const int lane = t & 63, wv = t >> 6;
    const int c0 = blockIdx.x * CH;
    const int cnt_total = min(CH, E - c0);

    for (int i = t; i < NBMAX; i += 256) hist[i] = 0;
    __syncthreads();
    #pragma unroll
    for (int p = 0; p < CH / 256; ++p) {
        int i = c0 + p * 256 + t;
        if (i < E) atomicAdd(&hist[dst[i] >> BSH], 1);
    }
    __syncthreads();
    {
        int b0 = 2 * t, b1 = 2 * t + 1;
        int h0 = hist[b0], h1 = hist[b1];
        int s = h0 + h1;
        int inc = s;
        #pragma unroll
        for (int d = 1; d < 64; d <<= 1) { int u = __shfl_up(inc, d); if (lane >= d) inc += u; }
        if (lane == 63) wt[wv] = inc;
        __syncthreads();
        int base = 0;
        for (int w2 = 0; w2 < wv; ++w2) base += wt[w2];
        int ex = base + inc - s;
        scan_[b0] = ex;
        scan_[b1] = ex + h0;
    }
    __syncthreads();
    for (int i = t; i < NBMAX; i += 256) {
        if (hist[i] > 0) gbase[i] = atomicAdd(&bcur[i], hist[i]);
        lcur[i] = scan_[i];
    }
    __syncthreads();
    #pragma unroll
    for (int p = 0; p < CH / 256; ++p) {
        int i = c0 + p * 256 + t;
        if (i < E) {
            int d = dst[i];
            int b = d >> BSH;
            int j = atomicAdd(&lcur[b], 1);
            recS[3 * j]     = src[i];
            recS[3 * j + 1] = d;
            recS[3 * j + 2] = __float_as_int(w[i]);
        }
    }
    __syncthreads();
    #pragma unroll
    for (int p = 0; p < CH / 256; ++p) {
        int j = p * 256 + t;
        if (j < cnt_total) {
            int d = recS[3 * j + 1];
            int b = d >> BSH;
            int g = gbase[b] + (j - scan_[b]);
            rec[3 * g]     = recS[3 * j];
            rec[3 * g + 1] = d;
            rec[3 * g + 2] = recS[3 * j + 2];
        }
    }
}

// ---------------- pass 4: per-bucket CSR build (LDS cursors) ----------------
__global__ __launch_bounds__(256)
void bucket_csr_kernel(const int* __restrict__ rec, const int* __restrict__ bbase,
                       int* __restrict__ off, int2* __restrict__ ed, int N) {
    __shared__ int h[BS];
    __shared__ int wt[4];
    const int b = blockIdx.x;
    const int t = threadIdx.x;
    const int lane = t & 63, wv = t >> 6;
    const int e0 = bbase[b], e1 = bbase[b + 1];
    const int n0 = b << BSH;
    const int nn = min(BS, N - n0);

    for (int i = t; i < BS; i += 256) h[i] = 0;
    __syncthreads();
    for (int i = e0 + t; i < e1; i += 256) atomicAdd(&h[rec[3 * i + 1] - n0], 1);
    __syncthreads();
    {
        int j0 = 4 * t;
        int l0 = h[j0], l1 = h[j0 + 1], l2 = h[j0 + 2], l3 = h[j0 + 3];
        int s = l0 + l1 + l2 + l3;
        int inc = s;
        #pragma unroll
        for (int d = 1; d < 64; d <<= 1) { int u = __shfl_up(inc, d); if (lane >= d) inc += u; }
        if (lane == 63) wt[wv] = inc;
        __syncthreads();
        int base = 0;
        for (int w2 = 0; w2 < wv; ++w2) base += wt[w2];
        int ex = base + inc - s;
        int e_[4] = {ex, ex + l0, ex + l0 + l1, ex + l0 + l1 + l2};
        __syncthreads();
        #pragma unroll
        for (int k = 0; k < 4; ++k) {
            h[j0 + k] = e_[k];
            if (j0 + k < nn) off[n0 + j0 + k] = e0 + e_[k];
        }
    }
    __syncthreads();
    for (int i = e0 + t; i < e1; i += 256) {
        int d = rec[3 * i + 1] - n0;
        int pos = atomicAdd(&h[d], 1);
        ed[e0 + pos] = make_int2(rec[3 * i], rec[3 * i + 2]);
    }
}

// ---------------- gather: ONE WAVE per node, 4-way edge split + shuffle reduce ----------------
__device__ __forceinline__ void acc8(float* a, int4 r, float w) {
    #pragma unroll
    for (int j = 0; j < 4; ++j) {
        int bits = (&r.x)[j];
        float f0 = __int_as_float(bits << 16);
        float f1 = __int_as_float(bits & 0xffff0000);
        a[2 * j]     += f0 * w;
        a[2 * j + 1] += f1 * w;
    }
}

__global__ __launch_bounds__(256)
void gather_wave(const unsigned short* __restrict__ X,
                 const int* __restrict__ off, const int2* __restrict__ ed,
                 const float* __restrict__ Dn,
                 unsigned short* __restrict__ outb, int N) {
    const int tid = threadIdx.x;
    const int n = blockIdx.x * 4 + (tid >> 6);    // one wave per node
    if (n >= N) return;
    const int lane = tid & 63;
    const int g2 = lane >> 4;                     // 0..3 edge-split group
    const int l = lane & 15;                      // 16 lanes x 16B = 256B row
    const int beg = off[n], end = off[n + 1];
    float a[8] = {0.f, 0.f, 0.f, 0.f, 0.f, 0.f, 0.f, 0.f};
    const unsigned short* Xc = X + 8 * l;
    int i = beg + g2;
    for (; i + 4 < end; i += 8) {                 // unroll 2: two loads in flight
        int2 e0 = ed[i];
        int2 e1 = ed[i + 4];
        int4 r0 = *(const int4*)(Xc + (long)e0.x * 128);
        int4 r1 = *(const int4*)(Xc + (long)e1.x * 128);
        acc8(a, r0, __int_as_float(e0.y));
        acc8(a, r1, __int_as_float(e1.y));
    }
    if (i < end) {
        int2 e0 = ed[i];
        int4 r0 = *(const int4*)(Xc + (long)e0.x * 128);
        acc8(a, r0, __int_as_float(e0.y));
    }
    // cross-group reduce: lanes l, l+16, l+32, l+48 hold partials for same cols
    #pragma unroll
    for (int j = 0; j < 8; ++j) {
        a[j] += __shfl_xor(a[j], 16);
        a[j] += __shfl_xor(a[j], 32);
    }
    if (g2 == 0) {
        const float dn = Dn[n];
        int4 o;
        #pragma unroll
        for (int j = 0; j < 4; ++j) {
            unsigned lo = f2bf(a[2 * j] * dn);
            unsigned hi = f2bf(a[2 * j + 1] * dn);
            (&o.x)[j] = (int)((hi << 16) | lo);
        }
        *(int4*)&outb[(long)n * 128 + 8 * l] = o;
    }
}

// ---------------- shared MFMA + LN epilogue ----------------
#define XS 136

__device__ __forceinline__ void stage_W(const float* __restrict__ Wf_hop, short* Wl, int tid) {
    const float4* W4 = (const float4*)Wf_hop;
    for (int idx = tid; idx < 128 * 32; idx += 256) {
        float4 v = W4[idx];
        int row = idx >> 5;
        int col = (idx & 31) * 4;
        short* p = &Wl[row * XS + col];
        p[0] = f2bf(v.x); p[1] = f2bf(v.y); p[2] = f2bf(v.z); p[3] = f2bf(v.w);
    }
}

__device__ __forceinline__ void mfma_ln_epilogue(
    const short* Xl, const short* Wl,
    const float* __restrict__ bp, const float* __restrict__ sp, const float* __restrict__ op,
    float* out, int ocol, int n0, int N, int tid)
{
    const int lane = tid & 63;
    const int wv = tid >> 6;
    f32x4 acc[8];
    #pragma unroll
    for (int c = 0; c < 8; ++c) acc[c] = (f32x4){0.f, 0.f, 0.f, 0.f};
    const int rsub = lane & 15;
    const int g = lane >> 4;
    const short* xbase = &Xl[(wv * 16 + rsub) * XS + g * 8];
    const short* wbase = &Wl[rsub * XS + g * 8];
    #pragma unroll
    for (int kk = 0; kk < 4; ++kk) {
        bf16x8 a = *(const bf16x8*)(xbase + kk * 32);
        #pragma unroll
        for (int c = 0; c < 8; ++c) {
            bf16x8 bb = *(const bf16x8*)(wbase + c * 16 * XS + kk * 32);
            acc[c] = __builtin_amdgcn_mfma_f32_16x16x32_bf16(a, bb, acc[c], 0, 0, 0);
        }
    }
    float sum[4] = {0.f, 0.f, 0.f, 0.f};
    float ssq[4] = {0.f, 0.f, 0.f, 0.f};
    #pragma unroll
    for (int c = 0; c < 8; ++c) {
        float bias = bp[c * 16 + rsub];
        #pragma unroll
        for (int r = 0; r < 4; ++r) {
            float h = acc[c][r] + bias;
            h = fmaxf(h, 0.0f);
            acc[c][r] = h;
            sum[r] += h;
            ssq[r] += h * h;
        }
    }
    #pragma unroll
    for (int msk = 1; msk < 16; msk <<= 1) {
        #pragma unroll
        for (int r = 0; r < 4; ++r) {
            sum[r] += __shfl_xor(sum[r], msk);
            ssq[r] += __shfl_xor(ssq[r], msk);
        }
    }
    #pragma unroll
    for (int r = 0; r < 4; ++r) {
        int n = n0 + wv * 16 + g * 4 + r;
        if (n >= N) continue;
        float mean = sum[r] * (1.0f / 128.0f);
        float var = ssq[r] * (1.0f / 128.0f) - mean * mean + EPSV;
        float inv = rsqrtf(var);
        float* orow = out + (long)n * OUT_STRIDE + ocol;
        #pragma unroll
        for (int c = 0; c < 8; ++c) {
            int col = c * 16 + rsub;
            orow[col] = (acc[c][r] - mean) * sp[col] * inv + op[col];
        }
    }
}

// ---------------- transform: all 3 hops from bf16 rows (blockIdx.y = hop) ----------------
__global__ __launch_bounds__(256)
void transform3_kernel(const unsigned short* __restrict__ featb,
                       const unsigned short* __restrict__ h1b,
                       const unsigned short* __restrict__ h2b,
                       const float* __restrict__ Wf,
                       const float* __restrict__ bf, const float* __restrict__ scf,
                       const float* __restrict__ offp,
                       float* out, int N)
{
    const int hop = blockIdx.y;
    const int tid = threadIdx.x;
    __shared__ __attribute__((aligned(16))) short Wl[128 * XS];
    __shared__ __attribute__((aligned(16))) short Xl[64 * XS];
    stage_W(Wf + (long)hop * 128 * 128, Wl, tid);
    const unsigned short* xb = (hop == 0) ? featb : (hop == 1) ? h1b : h2b;
    const int n0 = blockIdx.x * 64;
    for (int idx = tid; idx < 64 * 16; idx += 256) {
        int r = idx >> 4;
        int c = (idx & 15) * 8;
        int n = n0 + r;
        int4 v = make_int4(0, 0, 0, 0);
        if (n < N) v = *(const int4*)(xb + (long)n * 128 + c);
        *(int4*)&Xl[r * XS + c] = v;
    }
    __syncthreads();
    mfma_ln_epilogue(Xl, Wl, bf + hop * 128, scf + hop * 128, offp + hop * 128,
                     out, hop * 128, n0, N, tid);
}

// ---------------- fallback: push scatter + generic transform ----------------
__global__ __launch_bounds__(256)
void scatter_kernel(const float* X, long xstride, long xcol0,
                    const int* __restrict__ src, const int* __restrict__ dst,
                    const float* __restrict__ w, const float* __restrict__ Dn,
                    int useDn, float* out, long ocol0, int nE)
{
    const int lane = threadIdx.x & 63;
    const int wave = (int)((blockIdx.x * blockDim.x + threadIdx.x) >> 6);
    const int nWaves = (int)((gridDim.x * blockDim.x) >> 6);
    for (int e = wave; e < nE; e += nWaves) {
        const int s = src[e];
        const int d = dst[e];
        float ww = w[e];
        if (useDn) ww *= Dn[s];
        const float2 v = *(const float2*)(X + (long)s * xstride + xcol0 + 2 * lane);
        float* o = out + (long)d * OUT_STRIDE + ocol0 + 2 * lane;
        atomicAdd(o, v.x * ww);
        atomicAdd(o + 1, v.y * ww);
    }
}

__global__ __launch_bounds__(256)
void transform_f32_kernel(const float* x, long xs, int useDnIn,
                          const float* __restrict__ Dn,
                          const float* __restrict__ Wf_hop,
                          const float* __restrict__ bp, const float* __restrict__ sp,
                          const float* __restrict__ op,
                          float* out, int ocol, int N)
{
    __shared__ __attribute__((aligned(16))) short Wl[128 * XS];
    __shared__ __attribute__((aligned(16))) short Xl[64 * XS];
    const int tid = threadIdx.x;
    stage_W(Wf_hop, Wl, tid);
    const int n0 = blockIdx.x * 64;
    for (int idx = tid; idx < 64 * 32; idx += 256) {
        int r = idx >> 5;
        int col = (idx & 31) * 4;
        int n = n0 + r;
        float4 v = make_float4(0.f, 0.f, 0.f, 0.f);
        float m = 1.0f;
        if (n < N) {
            v = *(const float4*)(x + (long)n * xs + col);
            if (useDnIn) m = Dn[n];
        }
        short* p = &Xl[r * XS + col];
        p[0] = f2bf(v.x * m); p[1] = f2bf(v.y * m); p[2] = f2bf(v.z * m); p[3] = f2bf(v.w * m);
    }
    __syncthreads();
    mfma_ln_epilogue(Xl, Wl, bp, sp, op, out, ocol, n0, N, tid);
}

extern "C" void kernel_launch(void* const* d_in, const int* in_sizes, int n_in,
                              void* d_out, int out_size, void* d_ws, size_t ws_size,
                              hipStream_t stream) {
    const float* features = (const float*)d_in[0];
    const int*   src      = (const int*)d_in[1];
    const int*   dst      = (const int*)d_in[2];
    const float* w        = (const float*)d_in[3];
    const float* Dn       = (const float*)d_in[4];
    const float* W        = (const float*)d_in[5];
    const float* b        = (const float*)d_in[6];
    const float* scale    = (const float*)d_in[7];
    const float* offset   = (const float*)d_in[8];
    float* out = (float*)d_out;
    const int N = in_sizes[0] / 128;
    const int E = in_sizes[1];
    const int NB = (N + BS - 1) >> BSH;
    const int nblk = (N + 63) / 64;

    // ws layout (ints), no aliasing:
    // off[N+1] | ed[2E] | bcnt[NB] bbase[NB+1] bcur[NB] | rec[3E] | featb[64N] | h1b[64N] | h2b[64N]
    const size_t o_off = 0;
    const size_t o_ed  = ((size_t)N + 1 + 3) & ~(size_t)3;
    const size_t o_b   = o_ed + 2 * (size_t)E;
    const size_t o_rec = (o_b + 3 * (size_t)NB + 1 + 3) & ~(size_t)3;
    const size_t o_fb  = o_rec + 3 * (size_t)E;
    const size_t need  = (o_fb + 3 * (size_t)64 * N) * 4;

    if (NB <= NBMAX && ws_size >= need) {
        int* ws_i  = (int*)d_ws;
        int* off   = ws_i + o_off;
        int2* ed   = (int2*)(ws_i + o_ed);
        int* bcnt  = ws_i + o_b;
        int* bbase = bcnt + NB;
        int* bcur  = bbase + NB + 1;
        int* rec   = ws_i + o_rec;
        unsigned short* featb = (unsigned short*)(ws_i + o_fb);
        unsigned short* h1b   = featb + (size_t)N * 128;
        unsigned short* h2b   = h1b + (size_t)N * 128;

        hipMemsetAsync(bcnt, 0, (size_t)NB * 4, stream);
        bhist_pack_kernel<<<512, 256, 0, stream>>>(dst, bcnt, E, NB, features, featb, (long)N * 32);
        bscan_kernel<<<1, 256, 0, stream>>>(bcnt, bbase, bcur, off, NB, N, E);
        multisplit_kernel<<<(E + CH - 1) / CH, 256, 0, stream>>>(src, dst, w, bcur, rec, E);
        bucket_csr_kernel<<<NB, 256, 0, stream>>>(rec, bbase, off, ed, N);

        gather_wave<<<(N + 3) / 4, 256, 0, stream>>>(featb, off, ed, Dn, h1b, N);
        gather_wave<<<(N + 3) / 4, 256, 0, stream>>>(h1b, off, ed, Dn, h2b, N);

        dim3 tg(nblk, 3);
        transform3_kernel<<<tg, 256, 0, stream>>>(featb, h1b, h2b, W, b, scale, offset, out, N);
    } else {
        // fallback: atomic scatter path (raw agg stored; Dn applied on read)
        hipMemsetAsync(out, 0, (size_t)out_size * sizeof(float), stream);
        scatter_kernel<<<2048, 256, 0, stream>>>(features, 128, 0, src, dst, w, Dn, 0, out, 128, E);
        scatter_kernel<<<2048, 256, 0, stream>>>(out, OUT_STRIDE, 128, src, dst, w, Dn, 1, out, 256, E);
        transform_f32_kernel<<<nblk, 256, 0, stream>>>(features, 128, 0, Dn, W, b, scale, offset, out, 0, N);
        transform_f32_kernel<<<nblk, 256, 0, stream>>>(out + 128, OUT_STRIDE, 1, Dn, W + 128 * 128, b + 128, scale + 128, offset + 128, out, 128, N);
        transform_f32_kernel<<<nblk, 256, 0, stream>>>(out + 256, OUT_STRIDE, 1, Dn, W + 2 * 128 * 128, b + 256, scale + 256, offset + 256, out, 256, N);
    }
}

// Round 9
// 349.949 us; speedup vs baseline: 1.1489x; 1.0118x over previous
//
#include <hip/hip_runtime.h>
#include <hip/hip_bf16.h>

#define OUT_STRIDE 384
#define EPSV 1e-9f
#define BSH 10
#define BS 1024            // nodes per bucket
#define NBMAX 512
#define CH 4096            // edges per multisplit chunk

typedef __attribute__((ext_vector_type(8))) short bf16x8;
typedef __attribute__((ext_vector_type(4))) float f32x4;

static __device__ __forceinline__ unsigned short f2bf(float f) {
    __hip_bfloat16 h = __float2bfloat16(f);
    return *reinterpret_cast<unsigned short*>(&h);
}

// ---------------- multisplit (fixed-capacity buckets, direct global bump) + feature pack ----------------
__global__ __launch_bounds__(256)
void multisplit_pack_kernel(const int* __restrict__ src, const int* __restrict__ dst,
                            const float* __restrict__ w, int* __restrict__ bcur,
                            int* __restrict__ rec, int E, int CAP,
                            const float* __restrict__ features,
                            unsigned short* __restrict__ featb, long n4) {
    __shared__ int hist[NBMAX], scan_[NBMAX], gbase[NBMAX], lcur[NBMAX];
    __shared__ int recS[CH * 3];
    __shared__ int wt[4];
    const int t = threadIdx.x;
    const int lane = t & 63, wv = t >> 6;
    const int c0 = blockIdx.x * CH;
    const int cnt_total = min(CH, E - c0);

    for (int i = t; i < NBMAX; i += 256) hist[i] = 0;
    __syncthreads();
    #pragma unroll
    for (int p = 0; p < CH / 256; ++p) {
        int i = c0 + p * 256 + t;
        if (i < E) atomicAdd(&hist[dst[i] >> BSH], 1);
    }
    __syncthreads();
    {   // exclusive scan of hist[0..NBMAX)
        int b0 = 2 * t, b1 = 2 * t + 1;
        int h0 = hist[b0], h1 = hist[b1];
        int s = h0 + h1;
        int inc = s;
        #pragma unroll
        for (int d = 1; d < 64; d <<= 1) { int u = __shfl_up(inc, d); if (lane >= d) inc += u; }
        if (lane == 63) wt[wv] = inc;
        __syncthreads();
        int base = 0;
        for (int w2 = 0; w2 < wv; ++w2) base += wt[w2];
        int ex = base + inc - s;
        scan_[b0] = ex;
        scan_[b1] = ex + h0;
    }
    __syncthreads();
    for (int i = t; i < NBMAX; i += 256) {
        if (hist[i] > 0) gbase[i] = atomicAdd(&bcur[i], hist[i]);
        lcur[i] = scan_[i];
    }
    __syncthreads();
    #pragma unroll
    for (int p = 0; p < CH / 256; ++p) {
        int i = c0 + p * 256 + t;
        if (i < E) {
            int d = dst[i];
            int b = d >> BSH;
            int j = atomicAdd(&lcur[b], 1);
            recS[3 * j]     = src[i];
            recS[3 * j + 1] = d;
            recS[3 * j + 2] = __float_as_int(w[i]);
        }
    }
    __syncthreads();
    #pragma unroll
    for (int p = 0; p < CH / 256; ++p) {
        int j = p * 256 + t;
        if (j < cnt_total) {
            int d = recS[3 * j + 1];
            int b = d >> BSH;
            int g = gbase[b] + (j - scan_[b]);
            if (g < CAP) {                         // overflow clamp (deterministic)
                long gp = (long)b * CAP + g;
                rec[3 * gp]     = recS[3 * j];
                rec[3 * gp + 1] = d;
                rec[3 * gp + 2] = recS[3 * j + 2];
            }
        }
    }
    // independent stream: pack features f32 -> bf16
    long gid = blockIdx.x * blockDim.x + threadIdx.x;
    long stride = (long)gridDim.x * blockDim.x;
    for (long p = gid; p < n4; p += stride) {
        float4 v = ((const float4*)features)[p];
        ushort4 o;
        o.x = f2bf(v.x); o.y = f2bf(v.y); o.z = f2bf(v.z); o.w = f2bf(v.w);
        *(ushort4*)&featb[p * 4] = o;
    }
}

// ---------------- per-bucket CSR build (LDS cursors) ----------------
__global__ __launch_bounds__(256)
void bucket_csr_kernel(const int* __restrict__ rec, const int* __restrict__ bcur,
                       int* __restrict__ off, int* __restrict__ deg,
                       int2* __restrict__ ed, int N, int CAP) {
    __shared__ int h[BS];
    __shared__ int wt[4];
    const int b = blockIdx.x;
    const int t = threadIdx.x;
    const int lane = t & 63, wv = t >> 6;
    const int cnt = min(bcur[b], CAP);
    const long base = (long)b * CAP;
    const int n0 = b << BSH;
    const int nn = min(BS, N - n0);

    for (int i = t; i < BS; i += 256) h[i] = 0;
    __syncthreads();
    for (int i = t; i < cnt; i += 256) atomicAdd(&h[rec[3 * (base + i) + 1] - n0], 1);
    __syncthreads();
    {   // exclusive scan of h[0..BS), write off/deg
        int j0 = 4 * t;
        int l0 = h[j0], l1 = h[j0 + 1], l2 = h[j0 + 2], l3 = h[j0 + 3];
        int s = l0 + l1 + l2 + l3;
        int inc = s;
        #pragma unroll
        for (int d = 1; d < 64; d <<= 1) { int u = __shfl_up(inc, d); if (lane >= d) inc += u; }
        if (lane == 63) wt[wv] = inc;
        __syncthreads();
        int base_ = 0;
        for (int w2 = 0; w2 < wv; ++w2) base_ += wt[w2];
        int ex = base_ + inc - s;
        int e_[4] = {ex, ex + l0, ex + l0 + l1, ex + l0 + l1 + l2};
        int c_[4] = {l0, l1, l2, l3};
        __syncthreads();
        #pragma unroll
        for (int k = 0; k < 4; ++k) {
            h[j0 + k] = e_[k];
            if (j0 + k < nn) {
                off[n0 + j0 + k] = (int)(base + e_[k]);
                deg[n0 + j0 + k] = c_[k];
            }
        }
    }
    __syncthreads();
    for (int i = t; i < cnt; i += 256) {
        int d = rec[3 * (base + i) + 1] - n0;
        int pos = atomicAdd(&h[d], 1);
        ed[base + pos] = make_int2(rec[3 * (base + i)], rec[3 * (base + i) + 2]);
    }
}

// ---------------- gather: one wave per node, 4-way split, 4-wide unroll ----------------
__device__ __forceinline__ void acc8(float* a, int4 r, float w) {
    #pragma unroll
    for (int j = 0; j < 4; ++j) {
        int bits = (&r.x)[j];
        float f0 = __int_as_float(bits << 16);
        float f1 = __int_as_float(bits & 0xffff0000);
        a[2 * j]     += f0 * w;
        a[2 * j + 1] += f1 * w;
    }
}

__global__ __launch_bounds__(256)
void gather_wave(const unsigned short* __restrict__ X,
                 const int* __restrict__ off, const int* __restrict__ deg,
                 const int2* __restrict__ ed,
                 const float* __restrict__ Dn,
                 unsigned short* __restrict__ outb, int N) {
    const int tid = threadIdx.x;
    const int n = blockIdx.x * 4 + (tid >> 6);    // one wave per node
    if (n >= N) return;
    const int lane = tid & 63;
    const int g2 = lane >> 4;                     // 0..3 edge-split group
    const int l = lane & 15;                      // 16 lanes x 16B = 256B row
    const int beg = off[n];
    const int end = beg + deg[n];
    float a[8] = {0.f, 0.f, 0.f, 0.f, 0.f, 0.f, 0.f, 0.f};
    const unsigned short* Xc = X + 8 * l;
    int i = beg + g2;
    for (; i + 12 < end; i += 16) {               // 4 edges per group in flight
        int2 e0 = ed[i], e1 = ed[i + 4], e2 = ed[i + 8], e3 = ed[i + 12];
        int4 r0 = *(const int4*)(Xc + (long)e0.x * 128);
        int4 r1 = *(const int4*)(Xc + (long)e1.x * 128);
        int4 r2 = *(const int4*)(Xc + (long)e2.x * 128);
        int4 r3 = *(const int4*)(Xc + (long)e3.x * 128);
        acc8(a, r0, __int_as_float(e0.y));
        acc8(a, r1, __int_as_float(e1.y));
        acc8(a, r2, __int_as_float(e2.y));
        acc8(a, r3, __int_as_float(e3.y));
    }
    for (; i < end; i += 4) {
        int2 e0 = ed[i];
        int4 r0 = *(const int4*)(Xc + (long)e0.x * 128);
        acc8(a, r0, __int_as_float(e0.y));
    }
    #pragma unroll
    for (int j = 0; j < 8; ++j) {
        a[j] += __shfl_xor(a[j], 16);
        a[j] += __shfl_xor(a[j], 32);
    }
    if (g2 == 0) {
        const float dn = Dn[n];
        int4 o;
        #pragma unroll
        for (int j = 0; j < 4; ++j) {
            unsigned lo = f2bf(a[2 * j] * dn);
            unsigned hi = f2bf(a[2 * j + 1] * dn);
            (&o.x)[j] = (int)((hi << 16) | lo);
        }
        *(int4*)&outb[(long)n * 128 + 8 * l] = o;
    }
}

// ---------------- shared MFMA + LN epilogue ----------------
#define XS 136

__device__ __forceinline__ void stage_W(const float* __restrict__ Wf_hop, short* Wl, int tid) {
    const float4* W4 = (const float4*)Wf_hop;
    for (int idx = tid; idx < 128 * 32; idx += 256) {
        float4 v = W4[idx];
        int row = idx >> 5;
        int col = (idx & 31) * 4;
        short* p = &Wl[row * XS + col];
        p[0] = f2bf(v.x); p[1] = f2bf(v.y); p[2] = f2bf(v.z); p[3] = f2bf(v.w);
    }
}

__device__ __forceinline__ void mfma_ln_epilogue(
    const short* Xl, const short* Wl,
    const float* __restrict__ bp, const float* __restrict__ sp, const float* __restrict__ op,
    float* out, int ocol, int n0, int N, int tid)
{
    const int lane = tid & 63;
    const int wv = tid >> 6;
    f32x4 acc[8];
    #pragma unroll
    for (int c = 0; c < 8; ++c) acc[c] = (f32x4){0.f, 0.f, 0.f, 0.f};
    const int rsub = lane & 15;
    const int g = lane >> 4;
    const short* xbase = &Xl[(wv * 16 + rsub) * XS + g * 8];
    const short* wbase = &Wl[rsub * XS + g * 8];
    #pragma unroll
    for (int kk = 0; kk < 4; ++kk) {
        bf16x8 a = *(const bf16x8*)(xbase + kk * 32);
        #pragma unroll
        for (int c = 0; c < 8; ++c) {
            bf16x8 bb = *(const bf16x8*)(wbase + c * 16 * XS + kk * 32);
            acc[c] = __builtin_amdgcn_mfma_f32_16x16x32_bf16(a, bb, acc[c], 0, 0, 0);
        }
    }
    float sum[4] = {0.f, 0.f, 0.f, 0.f};
    float ssq[4] = {0.f, 0.f, 0.f, 0.f};
    #pragma unroll
    for (int c = 0; c < 8; ++c) {
        float bias = bp[c * 16 + rsub];
        #pragma unroll
        for (int r = 0; r < 4; ++r) {
            float h = acc[c][r] + bias;
            h = fmaxf(h, 0.0f);
            acc[c][r] = h;
            sum[r] += h;
            ssq[r] += h * h;
        }
    }
    #pragma unroll
    for (int msk = 1; msk < 16; msk <<= 1) {
        #pragma unroll
        for (int r = 0; r < 4; ++r) {
            sum[r] += __shfl_xor(sum[r], msk);
            ssq[r] += __shfl_xor(ssq[r], msk);
        }
    }
    #pragma unroll
    for (int r = 0; r < 4; ++r) {
        int n = n0 + wv * 16 + g * 4 + r;
        if (n >= N) continue;
        float mean = sum[r] * (1.0f / 128.0f);
        float var = ssq[r] * (1.0f / 128.0f) - mean * mean + EPSV;
        float inv = rsqrtf(var);
        float* orow = out + (long)n * OUT_STRIDE + ocol;
        #pragma unroll
        for (int c = 0; c < 8; ++c) {
            int col = c * 16 + rsub;
            orow[col] = (acc[c][r] - mean) * sp[col] * inv + op[col];
        }
    }
}

// ---------------- transform: all 3 hops from bf16 rows ----------------
__global__ __launch_bounds__(256)
void transform3_kernel(const unsigned short* __restrict__ featb,
                       const unsigned short* __restrict__ h1b,
                       const unsigned short* __restrict__ h2b,
                       const float* __restrict__ Wf,
                       const float* __restrict__ bf, const float* __restrict__ scf,
                       const float* __restrict__ offp,
                       float* out, int N)
{
    const int hop = blockIdx.y;
    const int tid = threadIdx.x;
    __shared__ __attribute__((aligned(16))) short Wl[128 * XS];
    __shared__ __attribute__((aligned(16))) short Xl[64 * XS];
    stage_W(Wf + (long)hop * 128 * 128, Wl, tid);
    const unsigned short* xb = (hop == 0) ? featb : (hop == 1) ? h1b : h2b;
    const int n0 = blockIdx.x * 64;
    for (int idx = tid; idx < 64 * 16; idx += 256) {
        int r = idx >> 4;
        int c = (idx & 15) * 8;
        int n = n0 + r;
        int4 v = make_int4(0, 0, 0, 0);
        if (n < N) v = *(const int4*)(xb + (long)n * 128 + c);
        *(int4*)&Xl[r * XS + c] = v;
    }
    __syncthreads();
    mfma_ln_epilogue(Xl, Wl, bf + hop * 128, scf + hop * 128, offp + hop * 128,
                     out, hop * 128, n0, N, tid);
}

// ---------------- fallback: push scatter + generic transform ----------------
__global__ __launch_bounds__(256)
void scatter_kernel(const float* X, long xstride, long xcol0,
                    const int* __restrict__ src, const int* __restrict__ dst,
                    const float* __restrict__ w, const float* __restrict__ Dn,
                    int useDn, float* out, long ocol0, int nE)
{
    const int lane = threadIdx.x & 63;
    const int wave = (int)((blockIdx.x * blockDim.x + threadIdx.x) >> 6);
    const int nWaves = (int)((gridDim.x * blockDim.x) >> 6);
    for (int e = wave; e < nE; e += nWaves) {
        const int s = src[e];
        const int d = dst[e];
        float ww = w[e];
        if (useDn) ww *= Dn[s];
        const float2 v = *(const float2*)(X + (long)s * xstride + xcol0 + 2 * lane);
        float* o = out + (long)d * OUT_STRIDE + ocol0 + 2 * lane;
        atomicAdd(o, v.x * ww);
        atomicAdd(o + 1, v.y * ww);
    }
}

__global__ __launch_bounds__(256)
void transform_f32_kernel(const float* x, long xs, int useDnIn,
                          const float* __restrict__ Dn,
                          const float* __restrict__ Wf_hop,
                          const float* __restrict__ bp, const float* __restrict__ sp,
                          const float* __restrict__ op,
                          float* out, int ocol, int N)
{
    __shared__ __attribute__((aligned(16))) short Wl[128 * XS];
    __shared__ __attribute__((aligned(16))) short Xl[64 * XS];
    const int tid = threadIdx.x;
    stage_W(Wf_hop, Wl, tid);
    const int n0 = blockIdx.x * 64;
    for (int idx = tid; idx < 64 * 32; idx += 256) {
        int r = idx >> 5;
        int col = (idx & 31) * 4;
        int n = n0 + r;
        float4 v = make_float4(0.f, 0.f, 0.f, 0.f);
        float m = 1.0f;
        if (n < N) {
            v = *(const float4*)(x + (long)n * xs + col);
            if (useDnIn) m = Dn[n];
        }
        short* p = &Xl[r * XS + col];
        p[0] = f2bf(v.x * m); p[1] = f2bf(v.y * m); p[2] = f2bf(v.z * m); p[3] = f2bf(v.w * m);
    }
    __syncthreads();
    mfma_ln_epilogue(Xl, Wl, bp, sp, op, out, ocol, n0, N, tid);
}

extern "C" void kernel_launch(void* const* d_in, const int* in_sizes, int n_in,
                              void* d_out, int out_size, void* d_ws, size_t ws_size,
                              hipStream_t stream) {
    const float* features = (const float*)d_in[0];
    const int*   src      = (const int*)d_in[1];
    const int*   dst      = (const int*)d_in[2];
    const float* w        = (const float*)d_in[3];
    const float* Dn       = (const float*)d_in[4];
    const float* W        = (const float*)d_in[5];
    const float* b        = (const float*)d_in[6];
    const float* scale    = (const float*)d_in[7];
    const float* offset   = (const float*)d_in[8];
    float* out = (float*)d_out;
    const int N = in_sizes[0] / 128;
    const int E = in_sizes[1];
    const int NB = (N + BS - 1) >> BSH;
    const int nblk = (N + 63) / 64;
    int CAP = ((E / (NB > 0 ? NB : 1)) * 3 / 2 + 255) & ~255;
    if (CAP < 1024) CAP = 1024;

    // ws layout (ints): off[N] | deg[N] | ed[2*NB*CAP] | bcur[NB] | rec[3*NB*CAP] | featb[64N] | h1b[64N] | h2b[64N]
    const size_t o_off = 0;
    const size_t o_deg = (size_t)N;
    const size_t o_ed  = ((size_t)2 * N + 3) & ~(size_t)3;
    const size_t o_bc  = o_ed + 2 * (size_t)NB * CAP;
    const size_t o_rec = (o_bc + NB + 3) & ~(size_t)3;
    const size_t o_fb  = o_rec + 3 * (size_t)NB * CAP;
    const size_t need  = (o_fb + 3 * (size_t)64 * N) * 4;

    if (NB <= NBMAX && ws_size >= need) {
        int* ws_i  = (int*)d_ws;
        int* off   = ws_i + o_off;
        int* deg   = ws_i + o_deg;
        int2* ed   = (int2*)(ws_i + o_ed);
        int* bcur  = ws_i + o_bc;
        int* rec   = ws_i + o_rec;
        unsigned short* featb = (unsigned short*)(ws_i + o_fb);
        unsigned short* h1b   = featb + (size_t)N * 128;
        unsigned short* h2b   = h1b + (size_t)N * 128;

        hipMemsetAsync(bcur, 0, (size_t)NB * 4, stream);
        multisplit_pack_kernel<<<(E + CH - 1) / CH, 256, 0, stream>>>(
            src, dst, w, bcur, rec, E, CAP, features, featb, (long)N * 32);
        bucket_csr_kernel<<<NB, 256, 0, stream>>>(rec, bcur, off, deg, ed, N, CAP);

        gather_wave<<<(N + 3) / 4, 256, 0, stream>>>(featb, off, deg, ed, Dn, h1b, N);
        gather_wave<<<(N + 3) / 4, 256, 0, stream>>>(h1b, off, deg, ed, Dn, h2b, N);

        dim3 tg(nblk, 3);
        transform3_kernel<<<tg, 256, 0, stream>>>(featb, h1b, h2b, W, b, scale, offset, out, N);
    } else {
        // fallback: atomic scatter path (raw agg stored; Dn applied on read)
        hipMemsetAsync(out, 0, (size_t)out_size * sizeof(float), stream);
        scatter_kernel<<<2048, 256, 0, stream>>>(features, 128, 0, src, dst, w, Dn, 0, out, 128, E);
        scatter_kernel<<<2048, 256, 0, stream>>>(out, OUT_STRIDE, 128, src, dst, w, Dn, 1, out, 256, E);
        transform_f32_kernel<<<nblk, 256, 0, stream>>>(features, 128, 0, Dn, W, b, scale, offset, out, 0, N);
        transform_f32_kernel<<<nblk, 256, 0, stream>>>(out + 128, OUT_STRIDE, 1, Dn, W + 128 * 128, b + 128, scale + 128, offset + 128, out, 128, N);
        transform_f32_kernel<<<nblk, 256, 0, stream>>>(out + 256, OUT_STRIDE, 1, Dn, W + 2 * 128 * 128, b + 256, scale + 256, offset + 256, out, 256, N);
    }
}

// Round 10
// 322.983 us; speedup vs baseline: 1.2448x; 1.0835x over previous
//
#include <hip/hip_runtime.h>
#include <hip/hip_bf16.h>

#define OUT_STRIDE 384
#define EPSV 1e-9f
#define BSH 9
#define BS 512             // nodes per bucket
#define NBMAX 512
#define CH 4096            // edges per multisplit chunk

typedef __attribute__((ext_vector_type(8))) short bf16x8;
typedef __attribute__((ext_vector_type(4))) float f32x4;

static __device__ __forceinline__ unsigned short f2bf(float f) {
    __hip_bfloat16 h = __float2bfloat16(f);
    return *reinterpret_cast<unsigned short*>(&h);
}

// ---------------- multisplit (fixed-capacity buckets) + feature pack ----------------
// writes edw[gp]=(src,w) and dl[gp]=dst for each edge, bucket-partitioned by dst>>BSH
__global__ __launch_bounds__(256)
void multisplit_pack_kernel(const int* __restrict__ src, const int* __restrict__ dst,
                            const float* __restrict__ w, int* __restrict__ bcur,
                            int2* __restrict__ edw, int* __restrict__ dl, int E, int CAP,
                            const float* __restrict__ features,
                            unsigned short* __restrict__ featb, long n4) {
    __shared__ int hist[NBMAX], scan_[NBMAX], gbase[NBMAX], lcur[NBMAX];
    __shared__ int recS[CH * 3];
    __shared__ int wt[4];
    const int t = threadIdx.x;
    const int lane = t & 63, wv = t >> 6;
    const int c0 = blockIdx.x * CH;
    const int cnt_total = min(CH, E - c0);

    for (int i = t; i < NBMAX; i += 256) hist[i] = 0;
    __syncthreads();
    #pragma unroll
    for (int p = 0; p < CH / 256; ++p) {
        int i = c0 + p * 256 + t;
        if (i < E) atomicAdd(&hist[dst[i] >> BSH], 1);
    }
    __syncthreads();
    {   // exclusive scan of hist[0..NBMAX)
        int b0 = 2 * t, b1 = 2 * t + 1;
        int h0 = hist[b0], h1 = hist[b1];
        int s = h0 + h1;
        int inc = s;
        #pragma unroll
        for (int d = 1; d < 64; d <<= 1) { int u = __shfl_up(inc, d); if (lane >= d) inc += u; }
        if (lane == 63) wt[wv] = inc;
        __syncthreads();
        int base = 0;
        for (int w2 = 0; w2 < wv; ++w2) base += wt[w2];
        int ex = base + inc - s;
        scan_[b0] = ex;
        scan_[b1] = ex + h0;
    }
    __syncthreads();
    for (int i = t; i < NBMAX; i += 256) {
        if (hist[i] > 0) gbase[i] = atomicAdd(&bcur[i], hist[i]);
        lcur[i] = scan_[i];
    }
    __syncthreads();
    #pragma unroll
    for (int p = 0; p < CH / 256; ++p) {
        int i = c0 + p * 256 + t;
        if (i < E) {
            int d = dst[i];
            int b = d >> BSH;
            int j = atomicAdd(&lcur[b], 1);
            recS[3 * j]     = src[i];
            recS[3 * j + 1] = d;
            recS[3 * j + 2] = __float_as_int(w[i]);
        }
    }
    __syncthreads();
    #pragma unroll
    for (int p = 0; p < CH / 256; ++p) {
        int j = p * 256 + t;
        if (j < cnt_total) {
            int d = recS[3 * j + 1];
            int b = d >> BSH;
            int g = gbase[b] + (j - scan_[b]);
            if (g < CAP) {                         // overflow clamp (deterministic)
                long gp = (long)b * CAP + g;
                edw[gp] = make_int2(recS[3 * j], recS[3 * j + 2]);
                dl[gp]  = d;
            }
        }
    }
    // independent stream: pack features f32 -> bf16
    long gid = blockIdx.x * blockDim.x + threadIdx.x;
    long stride = (long)gridDim.x * blockDim.x;
    for (long p = gid; p < n4; p += stride) {
        float4 v = ((const float4*)features)[p];
        ushort4 o;
        o.x = f2bf(v.x); o.y = f2bf(v.y); o.z = f2bf(v.z); o.w = f2bf(v.w);
        *(ushort4*)&featb[p * 4] = o;
    }
}

// ---------------- per-bucket CSR build (LDS cursors) ----------------
__global__ __launch_bounds__(256)
void bucket_csr_kernel(const int2* __restrict__ edw, const int* __restrict__ dl,
                       const int* __restrict__ bcur,
                       int* __restrict__ off, int* __restrict__ deg,
                       int2* __restrict__ ed, int N, int CAP) {
    __shared__ int h[BS];
    __shared__ int wt[4];
    const int b = blockIdx.x;
    const int t = threadIdx.x;
    const int lane = t & 63, wv = t >> 6;
    const int cnt = min(bcur[b], CAP);
    const long base = (long)b * CAP;
    const int n0 = b << BSH;
    const int nn = min(BS, N - n0);

    for (int i = t; i < BS; i += 256) h[i] = 0;
    __syncthreads();
    for (int i = t; i < cnt; i += 256) atomicAdd(&h[dl[base + i] - n0], 1);
    __syncthreads();
    {   // exclusive scan of h[0..BS), 2 per thread; write off/deg
        int j0 = 2 * t;
        int l0 = h[j0], l1 = h[j0 + 1];
        int s = l0 + l1;
        int inc = s;
        #pragma unroll
        for (int d = 1; d < 64; d <<= 1) { int u = __shfl_up(inc, d); if (lane >= d) inc += u; }
        if (lane == 63) wt[wv] = inc;
        __syncthreads();
        int base_ = 0;
        for (int w2 = 0; w2 < wv; ++w2) base_ += wt[w2];
        int ex = base_ + inc - s;
        int e0 = ex, e1 = ex + l0;
        __syncthreads();
        h[j0] = e0; h[j0 + 1] = e1;
        if (j0 < nn)     { off[n0 + j0]     = (int)(base + e0); deg[n0 + j0]     = l0; }
        if (j0 + 1 < nn) { off[n0 + j0 + 1] = (int)(base + e1); deg[n0 + j0 + 1] = l1; }
    }
    __syncthreads();
    for (int i = t; i < cnt; i += 256) {
        int d = dl[base + i] - n0;
        int pos = atomicAdd(&h[d], 1);
        ed[base + pos] = edw[base + i];
    }
}

// ---------------- gather: one wave per node, 4-way split, 4-wide unroll ----------------
__device__ __forceinline__ void acc8(float* a, int4 r, float w) {
    #pragma unroll
    for (int j = 0; j < 4; ++j) {
        int bits = (&r.x)[j];
        float f0 = __int_as_float(bits << 16);
        float f1 = __int_as_float(bits & 0xffff0000);
        a[2 * j]     += f0 * w;
        a[2 * j + 1] += f1 * w;
    }
}

__global__ __launch_bounds__(256)
void gather_wave(const unsigned short* __restrict__ X,
                 const int* __restrict__ off, const int* __restrict__ deg,
                 const int2* __restrict__ ed,
                 const float* __restrict__ Dn,
                 unsigned short* __restrict__ outb, int N) {
    const int tid = threadIdx.x;
    const int n = blockIdx.x * 4 + (tid >> 6);    // one wave per node
    if (n >= N) return;
    const int lane = tid & 63;
    const int g2 = lane >> 4;                     // 0..3 edge-split group
    const int l = lane & 15;                      // 16 lanes x 16B = 256B row
    const int beg = off[n];
    const int end = beg + deg[n];
    float a[8] = {0.f, 0.f, 0.f, 0.f, 0.f, 0.f, 0.f, 0.f};
    const unsigned short* Xc = X + 8 * l;
    int i = beg + g2;
    for (; i + 12 < end; i += 16) {               // 4 edges per group in flight
        int2 e0 = ed[i], e1 = ed[i + 4], e2 = ed[i + 8], e3 = ed[i + 12];
        int4 r0 = *(const int4*)(Xc + (long)e0.x * 128);
        int4 r1 = *(const int4*)(Xc + (long)e1.x * 128);
        int4 r2 = *(const int4*)(Xc + (long)e2.x * 128);
        int4 r3 = *(const int4*)(Xc + (long)e3.x * 128);
        acc8(a, r0, __int_as_float(e0.y));
        acc8(a, r1, __int_as_float(e1.y));
        acc8(a, r2, __int_as_float(e2.y));
        acc8(a, r3, __int_as_float(e3.y));
    }
    for (; i < end; i += 4) {
        int2 e0 = ed[i];
        int4 r0 = *(const int4*)(Xc + (long)e0.x * 128);
        acc8(a, r0, __int_as_float(e0.y));
    }
    #pragma unroll
    for (int j = 0; j < 8; ++j) {
        a[j] += __shfl_xor(a[j], 16);
        a[j] += __shfl_xor(a[j], 32);
    }
    if (g2 == 0) {
        const float dn = Dn[n];
        int4 o;
        #pragma unroll
        for (int j = 0; j < 4; ++j) {
            unsigned lo = f2bf(a[2 * j] * dn);
            unsigned hi = f2bf(a[2 * j + 1] * dn);
            (&o.x)[j] = (int)((hi << 16) | lo);
        }
        *(int4*)&outb[(long)n * 128 + 8 * l] = o;
    }
}

// ---------------- shared MFMA + LN epilogue ----------------
#define XS 136

__device__ __forceinline__ void stage_W(const float* __restrict__ Wf_hop, short* Wl, int tid) {
    const float4* W4 = (const float4*)Wf_hop;
    for (int idx = tid; idx < 128 * 32; idx += 256) {
        float4 v = W4[idx];
        int row = idx >> 5;
        int col = (idx & 31) * 4;
        short* p = &Wl[row * XS + col];
        p[0] = f2bf(v.x); p[1] = f2bf(v.y); p[2] = f2bf(v.z); p[3] = f2bf(v.w);
    }
}

__device__ __forceinline__ void mfma_ln_epilogue(
    const short* Xl, const short* Wl,
    const float* __restrict__ bp, const float* __restrict__ sp, const float* __restrict__ op,
    float* out, int ocol, int n0, int N, int tid)
{
    const int lane = tid & 63;
    const int wv = tid >> 6;
    f32x4 acc[8];
    #pragma unroll
    for (int c = 0; c < 8; ++c) acc[c] = (f32x4){0.f, 0.f, 0.f, 0.f};
    const int rsub = lane & 15;
    const int g = lane >> 4;
    const short* xbase = &Xl[(wv * 16 + rsub) * XS + g * 8];
    const short* wbase = &Wl[rsub * XS + g * 8];
    #pragma unroll
    for (int kk = 0; kk < 4; ++kk) {
        bf16x8 a = *(const bf16x8*)(xbase + kk * 32);
        #pragma unroll
        for (int c = 0; c < 8; ++c) {
            bf16x8 bb = *(const bf16x8*)(wbase + c * 16 * XS + kk * 32);
            acc[c] = __builtin_amdgcn_mfma_f32_16x16x32_bf16(a, bb, acc[c], 0, 0, 0);
        }
    }
    float sum[4] = {0.f, 0.f, 0.f, 0.f};
    float ssq[4] = {0.f, 0.f, 0.f, 0.f};
    #pragma unroll
    for (int c = 0; c < 8; ++c) {
        float bias = bp[c * 16 + rsub];
        #pragma unroll
        for (int r = 0; r < 4; ++r) {
            float h = acc[c][r] + bias;
            h = fmaxf(h, 0.0f);
            acc[c][r] = h;
            sum[r] += h;
            ssq[r] += h * h;
        }
    }
    #pragma unroll
    for (int msk = 1; msk < 16; msk <<= 1) {
        #pragma unroll
        for (int r = 0; r < 4; ++r) {
            sum[r] += __shfl_xor(sum[r], msk);
            ssq[r] += __shfl_xor(ssq[r], msk);
        }
    }
    #pragma unroll
    for (int r = 0; r < 4; ++r) {
        int n = n0 + wv * 16 + g * 4 + r;
        if (n >= N) continue;
        float mean = sum[r] * (1.0f / 128.0f);
        float var = ssq[r] * (1.0f / 128.0f) - mean * mean + EPSV;
        float inv = rsqrtf(var);
        float* orow = out + (long)n * OUT_STRIDE + ocol;
        #pragma unroll
        for (int c = 0; c < 8; ++c) {
            int col = c * 16 + rsub;
            orow[col] = (acc[c][r] - mean) * sp[col] * inv + op[col];
        }
    }
}

// ---------------- transform: all 3 hops from bf16 rows, 2 row-tiles per block ----------------
__global__ __launch_bounds__(256)
void transform3_kernel(const unsigned short* __restrict__ featb,
                       const unsigned short* __restrict__ h1b,
                       const unsigned short* __restrict__ h2b,
                       const float* __restrict__ Wf,
                       const float* __restrict__ bf, const float* __restrict__ scf,
                       const float* __restrict__ offp,
                       float* out, int N)
{
    const int hop = blockIdx.y;
    const int tid = threadIdx.x;
    __shared__ __attribute__((aligned(16))) short Wl[128 * XS];
    __shared__ __attribute__((aligned(16))) short Xl[64 * XS];
    stage_W(Wf + (long)hop * 128 * 128, Wl, tid);
    const unsigned short* xb = (hop == 0) ? featb : (hop == 1) ? h1b : h2b;
    #pragma unroll
    for (int t2 = 0; t2 < 2; ++t2) {
        const int n0 = (blockIdx.x * 2 + t2) * 64;
        for (int idx = tid; idx < 64 * 16; idx += 256) {
            int r = idx >> 4;
            int c = (idx & 15) * 8;
            int n = n0 + r;
            int4 v = make_int4(0, 0, 0, 0);
            if (n < N) v = *(const int4*)(xb + (long)n * 128 + c);
            *(int4*)&Xl[r * XS + c] = v;
        }
        __syncthreads();
        mfma_ln_epilogue(Xl, Wl, bf + hop * 128, scf + hop * 128, offp + hop * 128,
                         out, hop * 128, n0, N, tid);
        __syncthreads();
    }
}

// ---------------- fallback: push scatter + generic transform ----------------
__global__ __launch_bounds__(256)
void scatter_kernel(const float* X, long xstride, long xcol0,
                    const int* __restrict__ src, const int* __restrict__ dst,
                    const float* __restrict__ w, const float* __restrict__ Dn,
                    int useDn, float* out, long ocol0, int nE)
{
    const int lane = threadIdx.x & 63;
    const int wave = (int)((blockIdx.x * blockDim.x + threadIdx.x) >> 6);
    const int nWaves = (int)((gridDim.x * blockDim.x) >> 6);
    for (int e = wave; e < nE; e += nWaves) {
        const int s = src[e];
        const int d = dst[e];
        float ww = w[e];
        if (useDn) ww *= Dn[s];
        const float2 v = *(const float2*)(X + (long)s * xstride + xcol0 + 2 * lane);
        float* o = out + (long)d * OUT_STRIDE + ocol0 + 2 * lane;
        atomicAdd(o, v.x * ww);
        atomicAdd(o + 1, v.y * ww);
    }
}

__global__ __launch_bounds__(256)
void transform_f32_kernel(const float* x, long xs, int useDnIn,
                          const float* __restrict__ Dn,
                          const float* __restrict__ Wf_hop,
                          const float* __restrict__ bp, const float* __restrict__ sp,
                          const float* __restrict__ op,
                          float* out, int ocol, int N)
{
    __shared__ __attribute__((aligned(16))) short Wl[128 * XS];
    __shared__ __attribute__((aligned(16))) short Xl[64 * XS];
    const int tid = threadIdx.x;
    stage_W(Wf_hop, Wl, tid);
    const int n0 = blockIdx.x * 64;
    for (int idx = tid; idx < 64 * 32; idx += 256) {
        int r = idx >> 5;
        int col = (idx & 31) * 4;
        int n = n0 + r;
        float4 v = make_float4(0.f, 0.f, 0.f, 0.f);
        float m = 1.0f;
        if (n < N) {
            v = *(const float4*)(x + (long)n * xs + col);
            if (useDnIn) m = Dn[n];
        }
        short* p = &Xl[r * XS + col];
        p[0] = f2bf(v.x * m); p[1] = f2bf(v.y * m); p[2] = f2bf(v.z * m); p[3] = f2bf(v.w * m);
    }
    __syncthreads();
    mfma_ln_epilogue(Xl, Wl, bp, sp, op, out, ocol, n0, N, tid);
}

extern "C" void kernel_launch(void* const* d_in, const int* in_sizes, int n_in,
                              void* d_out, int out_size, void* d_ws, size_t ws_size,
                              hipStream_t stream) {
    const float* features = (const float*)d_in[0];
    const int*   src      = (const int*)d_in[1];
    const int*   dst      = (const int*)d_in[2];
    const float* w        = (const float*)d_in[3];
    const float* Dn       = (const float*)d_in[4];
    const float* W        = (const float*)d_in[5];
    const float* b        = (const float*)d_in[6];
    const float* scale    = (const float*)d_in[7];
    const float* offset   = (const float*)d_in[8];
    float* out = (float*)d_out;
    const int N = in_sizes[0] / 128;
    const int E = in_sizes[1];
    const int NB = (N + BS - 1) >> BSH;
    const int nblk = (N + 63) / 64;
    int CAP = ((E / (NB > 0 ? NB : 1)) * 3 / 2 + 255) & ~255;
    if (CAP < 1024) CAP = 1024;
    const size_t NC = (size_t)NB * CAP;

    // ws layout (ints): off[N] deg[N] | ed[2NC] | bcur[NB] | edw[2NC] | dl[NC] | featb[64N] h1b[64N] h2b[64N]
    const size_t o_off = 0;
    const size_t o_deg = (size_t)N;
    const size_t o_ed  = ((size_t)2 * N + 3) & ~(size_t)3;
    const size_t o_bc  = o_ed + 2 * NC;
    const size_t o_un  = (o_bc + NB + 3) & ~(size_t)3;
    const size_t o_dl  = o_un + 2 * NC;
    const size_t o_fb  = o_dl + NC;
    const size_t need  = (o_fb + 3 * (size_t)64 * N) * 4;

    if (NB <= NBMAX && ws_size >= need) {
        int* ws_i  = (int*)d_ws;
        int* off   = ws_i + o_off;
        int* deg   = ws_i + o_deg;
        int2* ed   = (int2*)(ws_i + o_ed);
        int* bcur  = ws_i + o_bc;
        int2* edw  = (int2*)(ws_i + o_un);
        int* dl    = ws_i + o_dl;
        unsigned short* featb = (unsigned short*)(ws_i + o_fb);
        unsigned short* h1b   = featb + (size_t)N * 128;
        unsigned short* h2b   = h1b + (size_t)N * 128;

        hipMemsetAsync(bcur, 0, (size_t)NB * 4, stream);
        multisplit_pack_kernel<<<(E + CH - 1) / CH, 256, 0, stream>>>(
            src, dst, w, bcur, edw, dl, E, CAP, features, featb, (long)N * 32);
        bucket_csr_kernel<<<NB, 256, 0, stream>>>(edw, dl, bcur, off, deg, ed, N, CAP);

        gather_wave<<<(N + 3) / 4, 256, 0, stream>>>(featb, off, deg, ed, Dn, h1b, N);
        gather_wave<<<(N + 3) / 4, 256, 0, stream>>>(h1b, off, deg, ed, Dn, h2b, N);

        dim3 tg((N + 127) / 128, 3);
        transform3_kernel<<<tg, 256, 0, stream>>>(featb, h1b, h2b, W, b, scale, offset, out, N);
    } else {
        // fallback: atomic scatter path (raw agg stored; Dn applied on read)
        hipMemsetAsync(out, 0, (size_t)out_size * sizeof(float), stream);
        scatter_kernel<<<2048, 256, 0, stream>>>(features, 128, 0, src, dst, w, Dn, 0, out, 128, E);
        scatter_kernel<<<2048, 256, 0, stream>>>(out, OUT_STRIDE, 128, src, dst, w, Dn, 1, out, 256, E);
        transform_f32_kernel<<<nblk, 256, 0, stream>>>(features, 128, 0, Dn, W, b, scale, offset, out, 0, N);
        transform_f32_kernel<<<nblk, 256, 0, stream>>>(out + 128, OUT_STRIDE, 1, Dn, W + 128 * 128, b + 128, scale + 128, offset + 128, out, 128, N);
        transform_f32_kernel<<<nblk, 256, 0, stream>>>(out + 256, OUT_STRIDE, 1, Dn, W + 2 * 128 * 128, b + 256, scale + 256, offset + 256, out, 256, N);
    }
}

// Round 11
// 306.591 us; speedup vs baseline: 1.3114x; 1.0535x over previous
//
#include <hip/hip_runtime.h>
#include <hip/hip_bf16.h>

#define OUT_STRIDE 384
#define EPSV 1e-9f
#define BSH 9
#define BS 512             // nodes per bucket
#define NBMAX 512
#define CH 4096            // edges per multisplit chunk

typedef __attribute__((ext_vector_type(8))) short bf16x8;
typedef __attribute__((ext_vector_type(4))) float f32x4;

static __device__ __forceinline__ unsigned short f2bf(float f) {
    __hip_bfloat16 h = __float2bfloat16(f);
    return *reinterpret_cast<unsigned short*>(&h);
}

// ---------------- multisplit (fixed-capacity buckets) + feature pack ----------------
// writes edw[gp]=(src,w) and dlu[gp]=local dst for each edge, bucket-partitioned by dst>>BSH
__global__ __launch_bounds__(256)
void multisplit_pack_kernel(const int* __restrict__ src, const int* __restrict__ dst,
                            const float* __restrict__ w, int* __restrict__ bcur,
                            int2* __restrict__ edw, unsigned short* __restrict__ dlu,
                            int E, int CAP,
                            const float* __restrict__ features,
                            unsigned short* __restrict__ featb, long n4) {
    __shared__ int hist[NBMAX], scan_[NBMAX], gbase[NBMAX], lcur[NBMAX];
    __shared__ int recS[CH * 3];
    __shared__ int wt[4];
    const int t = threadIdx.x;
    const int lane = t & 63, wv = t >> 6;
    const int c0 = blockIdx.x * CH;
    const int cnt_total = min(CH, E - c0);

    for (int i = t; i < NBMAX; i += 256) hist[i] = 0;
    __syncthreads();
    #pragma unroll
    for (int p = 0; p < CH / 256; ++p) {
        int i = c0 + p * 256 + t;
        if (i < E) atomicAdd(&hist[dst[i] >> BSH], 1);
    }
    __syncthreads();
    {   // exclusive scan of hist[0..NBMAX)
        int b0 = 2 * t, b1 = 2 * t + 1;
        int h0 = hist[b0], h1 = hist[b1];
        int s = h0 + h1;
        int inc = s;
        #pragma unroll
        for (int d = 1; d < 64; d <<= 1) { int u = __shfl_up(inc, d); if (lane >= d) inc += u; }
        if (lane == 63) wt[wv] = inc;
        __syncthreads();
        int base = 0;
        for (int w2 = 0; w2 < wv; ++w2) base += wt[w2];
        int ex = base + inc - s;
        scan_[b0] = ex;
        scan_[b1] = ex + h0;
    }
    __syncthreads();
    for (int i = t; i < NBMAX; i += 256) {
        if (hist[i] > 0) gbase[i] = atomicAdd(&bcur[i], hist[i]);
        lcur[i] = scan_[i];
    }
    __syncthreads();
    #pragma unroll
    for (int p = 0; p < CH / 256; ++p) {
        int i = c0 + p * 256 + t;
        if (i < E) {
            int d = dst[i];
            int b = d >> BSH;
            int j = atomicAdd(&lcur[b], 1);
            recS[3 * j]     = src[i];
            recS[3 * j + 1] = d;
            recS[3 * j + 2] = __float_as_int(w[i]);
        }
    }
    __syncthreads();
    #pragma unroll
    for (int p = 0; p < CH / 256; ++p) {
        int j = p * 256 + t;
        if (j < cnt_total) {
            int d = recS[3 * j + 1];
            int b = d >> BSH;
            int g = gbase[b] + (j - scan_[b]);
            if (g < CAP) {                         // overflow clamp (deterministic)
                long gp = (long)b * CAP + g;
                edw[gp] = make_int2(recS[3 * j], recS[3 * j + 2]);
                dlu[gp] = (unsigned short)(d - (b << BSH));
            }
        }
    }
    // independent stream: pack features f32 -> bf16
    long gid = blockIdx.x * blockDim.x + threadIdx.x;
    long stride = (long)gridDim.x * blockDim.x;
    for (long p = gid; p < n4; p += stride) {
        float4 v = ((const float4*)features)[p];
        ushort4 o;
        o.x = f2bf(v.x); o.y = f2bf(v.y); o.z = f2bf(v.z); o.w = f2bf(v.w);
        *(ushort4*)&featb[p * 4] = o;
    }
}

// ---------------- per-bucket CSR build (LDS cursors) ----------------
__global__ __launch_bounds__(256)
void bucket_csr_kernel(const int2* __restrict__ edw, const unsigned short* __restrict__ dlu,
                       const int* __restrict__ bcur,
                       int* __restrict__ off, int* __restrict__ deg,
                       int2* __restrict__ ed, int N, int CAP) {
    __shared__ int h[BS];
    __shared__ int wt[4];
    const int b = blockIdx.x;
    const int t = threadIdx.x;
    const int lane = t & 63, wv = t >> 6;
    const int cnt = min(bcur[b], CAP);
    const long base = (long)b * CAP;
    const int n0 = b << BSH;
    const int nn = min(BS, N - n0);

    for (int i = t; i < BS; i += 256) h[i] = 0;
    __syncthreads();
    for (int i = t; i < cnt; i += 256) atomicAdd(&h[dlu[base + i]], 1);
    __syncthreads();
    {   // exclusive scan of h[0..BS), 2 per thread; write off/deg
        int j0 = 2 * t;
        int l0 = h[j0], l1 = h[j0 + 1];
        int s = l0 + l1;
        int inc = s;
        #pragma unroll
        for (int d = 1; d < 64; d <<= 1) { int u = __shfl_up(inc, d); if (lane >= d) inc += u; }
        if (lane == 63) wt[wv] = inc;
        __syncthreads();
        int base_ = 0;
        for (int w2 = 0; w2 < wv; ++w2) base_ += wt[w2];
        int ex = base_ + inc - s;
        int e0 = ex, e1 = ex + l0;
        __syncthreads();
        h[j0] = e0; h[j0 + 1] = e1;
        if (j0 < nn)     { off[n0 + j0]     = (int)(base + e0); deg[n0 + j0]     = l0; }
        if (j0 + 1 < nn) { off[n0 + j0 + 1] = (int)(base + e1); deg[n0 + j0 + 1] = l1; }
    }
    __syncthreads();
    for (int i = t; i < cnt; i += 256) {
        int d = dlu[base + i];
        int pos = atomicAdd(&h[d], 1);
        ed[base + pos] = edw[base + i];
    }
}

// ---------------- gather: one wave per node, 4-way split, 4-wide unroll ----------------
// ed/off/deg are single-use streams -> nontemporal loads, preserving L2 for the row table X.
__device__ __forceinline__ void acc8(float* a, int4 r, float w) {
    #pragma unroll
    for (int j = 0; j < 4; ++j) {
        int bits = (&r.x)[j];
        float f0 = __int_as_float(bits << 16);
        float f1 = __int_as_float(bits & 0xffff0000);
        a[2 * j]     += f0 * w;
        a[2 * j + 1] += f1 * w;
    }
}

__device__ __forceinline__ int2 nt_ld_int2(const int2* p) {
    long v = __builtin_nontemporal_load((const long*)p);
    int2 r; r.x = (int)(v & 0xffffffffL); r.y = (int)(((unsigned long)v) >> 32);
    return r;
}

__global__ __launch_bounds__(256)
void gather_wave(const unsigned short* __restrict__ X,
                 const int* __restrict__ off, const int* __restrict__ deg,
                 const int2* __restrict__ ed,
                 const float* __restrict__ Dn,
                 unsigned short* __restrict__ outb, int N) {
    const int tid = threadIdx.x;
    const int n = blockIdx.x * 4 + (tid >> 6);    // one wave per node
    if (n >= N) return;
    const int lane = tid & 63;
    const int g2 = lane >> 4;                     // 0..3 edge-split group
    const int l = lane & 15;                      // 16 lanes x 16B = 256B row
    const int beg = __builtin_nontemporal_load(&off[n]);
    const int end = beg + __builtin_nontemporal_load(&deg[n]);
    float a[8] = {0.f, 0.f, 0.f, 0.f, 0.f, 0.f, 0.f, 0.f};
    const unsigned short* Xc = X + 8 * l;
    int i = beg + g2;
    for (; i + 12 < end; i += 16) {               // 4 edges per group in flight
        int2 e0 = nt_ld_int2(&ed[i]);
        int2 e1 = nt_ld_int2(&ed[i + 4]);
        int2 e2 = nt_ld_int2(&ed[i + 8]);
        int2 e3 = nt_ld_int2(&ed[i + 12]);
        int4 r0 = *(const int4*)(Xc + (long)e0.x * 128);
        int4 r1 = *(const int4*)(Xc + (long)e1.x * 128);
        int4 r2 = *(const int4*)(Xc + (long)e2.x * 128);
        int4 r3 = *(const int4*)(Xc + (long)e3.x * 128);
        acc8(a, r0, __int_as_float(e0.y));
        acc8(a, r1, __int_as_float(e1.y));
        acc8(a, r2, __int_as_float(e2.y));
        acc8(a, r3, __int_as_float(e3.y));
    }
    for (; i < end; i += 4) {
        int2 e0 = nt_ld_int2(&ed[i]);
        int4 r0 = *(const int4*)(Xc + (long)e0.x * 128);
        acc8(a, r0, __int_as_float(e0.y));
    }
    #pragma unroll
    for (int j = 0; j < 8; ++j) {
        a[j] += __shfl_xor(a[j], 16);
        a[j] += __shfl_xor(a[j], 32);
    }
    if (g2 == 0) {
        const float dn = Dn[n];
        int4 o;
        #pragma unroll
        for (int j = 0; j < 4; ++j) {
            unsigned lo = f2bf(a[2 * j] * dn);
            unsigned hi = f2bf(a[2 * j + 1] * dn);
            (&o.x)[j] = (int)((hi << 16) | lo);
        }
        *(int4*)&outb[(long)n * 128 + 8 * l] = o;
    }
}

// ---------------- shared MFMA + LN epilogue ----------------
#define XS 136

__device__ __forceinline__ void stage_W(const float* __restrict__ Wf_hop, short* Wl, int tid) {
    const float4* W4 = (const float4*)Wf_hop;
    for (int idx = tid; idx < 128 * 32; idx += 256) {
        float4 v = W4[idx];
        int row = idx >> 5;
        int col = (idx & 31) * 4;
        short* p = &Wl[row * XS + col];
        p[0] = f2bf(v.x); p[1] = f2bf(v.y); p[2] = f2bf(v.z); p[3] = f2bf(v.w);
    }
}

__device__ __forceinline__ void mfma_ln_epilogue(
    const short* Xl, const short* Wl,
    const float* __restrict__ bp, const float* __restrict__ sp, const float* __restrict__ op,
    float* out, int ocol, int n0, int N, int tid)
{
    const int lane = tid & 63;
    const int wv = tid >> 6;
    f32x4 acc[8];
    #pragma unroll
    for (int c = 0; c < 8; ++c) acc[c] = (f32x4){0.f, 0.f, 0.f, 0.f};
    const int rsub = lane & 15;
    const int g = lane >> 4;
    const short* xbase = &Xl[(wv * 16 + rsub) * XS + g * 8];
    const short* wbase = &Wl[rsub * XS + g * 8];
    #pragma unroll
    for (int kk = 0; kk < 4; ++kk) {
        bf16x8 a = *(const bf16x8*)(xbase + kk * 32);
        #pragma unroll
        for (int c = 0; c < 8; ++c) {
            bf16x8 bb = *(const bf16x8*)(wbase + c * 16 * XS + kk * 32);
            acc[c] = __builtin_amdgcn_mfma_f32_16x16x32_bf16(a, bb, acc[c], 0, 0, 0);
        }
    }
    float sum[4] = {0.f, 0.f, 0.f, 0.f};
    float ssq[4] = {0.f, 0.f, 0.f, 0.f};
    #pragma unroll
    for (int c = 0; c < 8; ++c) {
        float bias = bp[c * 16 + rsub];
        #pragma unroll
        for (int r = 0; r < 4; ++r) {
            float h = acc[c][r] + bias;
            h = fmaxf(h, 0.0f);
            acc[c][r] = h;
            sum[r] += h;
            ssq[r] += h * h;
        }
    }
    #pragma unroll
    for (int msk = 1; msk < 16; msk <<= 1) {
        #pragma unroll
        for (int r = 0; r < 4; ++r) {
            sum[r] += __shfl_xor(sum[r], msk);
            ssq[r] += __shfl_xor(ssq[r], msk);
        }
    }
    #pragma unroll
    for (int r = 0; r < 4; ++r) {
        int n = n0 + wv * 16 + g * 4 + r;
        if (n >= N) continue;
        float mean = sum[r] * (1.0f / 128.0f);
        float var = ssq[r] * (1.0f / 128.0f) - mean * mean + EPSV;
        float inv = rsqrtf(var);
        float* orow = out + (long)n * OUT_STRIDE + ocol;
        #pragma unroll
        for (int c = 0; c < 8; ++c) {
            int col = c * 16 + rsub;
            __builtin_nontemporal_store((acc[c][r] - mean) * sp[col] * inv + op[col], &orow[col]);
        }
    }
}

// ---------------- transform: all 3 hops from bf16 rows, 2 row-tiles per block ----------------
__global__ __launch_bounds__(256)
void transform3_kernel(const unsigned short* __restrict__ featb,
                       const unsigned short* __restrict__ h1b,
                       const unsigned short* __restrict__ h2b,
                       const float* __restrict__ Wf,
                       const float* __restrict__ bf, const float* __restrict__ scf,
                       const float* __restrict__ offp,
                       float* out, int N)
{
    const int hop = blockIdx.y;
    const int tid = threadIdx.x;
    __shared__ __attribute__((aligned(16))) short Wl[128 * XS];
    __shared__ __attribute__((aligned(16))) short Xl[64 * XS];
    stage_W(Wf + (long)hop * 128 * 128, Wl, tid);
    const unsigned short* xb = (hop == 0) ? featb : (hop == 1) ? h1b : h2b;
    #pragma unroll
    for (int t2 = 0; t2 < 2; ++t2) {
        const int n0 = (blockIdx.x * 2 + t2) * 64;
        for (int idx = tid; idx < 64 * 16; idx += 256) {
            int r = idx >> 4;
            int c = (idx & 15) * 8;
            int n = n0 + r;
            int4 v = make_int4(0, 0, 0, 0);
            if (n < N) v = *(const int4*)(xb + (long)n * 128 + c);
            *(int4*)&Xl[r * XS + c] = v;
        }
        __syncthreads();
        mfma_ln_epilogue(Xl, Wl, bf + hop * 128, scf + hop * 128, offp + hop * 128,
                         out, hop * 128, n0, N, tid);
        __syncthreads();
    }
}

// ---------------- fallback: push scatter + generic transform ----------------
__global__ __launch_bounds__(256)
void scatter_kernel(const float* X, long xstride, long xcol0,
                    const int* __restrict__ src, const int* __restrict__ dst,
                    const float* __restrict__ w, const float* __restrict__ Dn,
                    int useDn, float* out, long ocol0, int nE)
{
    const int lane = threadIdx.x & 63;
    const int wave = (int)((blockIdx.x * blockDim.x + threadIdx.x) >> 6);
    const int nWaves = (int)((gridDim.x * blockDim.x) >> 6);
    for (int e = wave; e < nE; e += nWaves) {
        const int s = src[e];
        const int d = dst[e];
        float ww = w[e];
        if (useDn) ww *= Dn[s];
        const float2 v = *(const float2*)(X + (long)s * xstride + xcol0 + 2 * lane);
        float* o = out + (long)d * OUT_STRIDE + ocol0 + 2 * lane;
        atomicAdd(o, v.x * ww);
        atomicAdd(o + 1, v.y * ww);
    }
}

__global__ __launch_bounds__(256)
void transform_f32_kernel(const float* x, long xs, int useDnIn,
                          const float* __restrict__ Dn,
                          const float* __restrict__ Wf_hop,
                          const float* __restrict__ bp, const float* __restrict__ sp,
                          const float* __restrict__ op,
                          float* out, int ocol, int N)
{
    __shared__ __attribute__((aligned(16))) short Wl[128 * XS];
    __shared__ __attribute__((aligned(16))) short Xl[64 * XS];
    const int tid = threadIdx.x;
    stage_W(Wf_hop, Wl, tid);
    const int n0 = blockIdx.x * 64;
    for (int idx = tid; idx < 64 * 32; idx += 256) {
        int r = idx >> 5;
        int col = (idx & 31) * 4;
        int n = n0 + r;
        float4 v = make_float4(0.f, 0.f, 0.f, 0.f);
        float m = 1.0f;
        if (n < N) {
            v = *(const float4*)(x + (long)n * xs + col);
            if (useDnIn) m = Dn[n];
        }
        short* p = &Xl[r * XS + col];
        p[0] = f2bf(v.x * m); p[1] = f2bf(v.y * m); p[2] = f2bf(v.z * m); p[3] = f2bf(v.w * m);
    }
    __syncthreads();
    mfma_ln_epilogue(Xl, Wl, bp, sp, op, out, ocol, n0, N, tid);
}

extern "C" void kernel_launch(void* const* d_in, const int* in_sizes, int n_in,
                              void* d_out, int out_size, void* d_ws, size_t ws_size,
                              hipStream_t stream) {
    const float* features = (const float*)d_in[0];
    const int*   src      = (const int*)d_in[1];
    const int*   dst      = (const int*)d_in[2];
    const float* w        = (const float*)d_in[3];
    const float* Dn       = (const float*)d_in[4];
    const float* W        = (const float*)d_in[5];
    const float* b        = (const float*)d_in[6];
    const float* scale    = (const float*)d_in[7];
    const float* offset   = (const float*)d_in[8];
    float* out = (float*)d_out;
    const int N = in_sizes[0] / 128;
    const int E = in_sizes[1];
    const int NB = (N + BS - 1) >> BSH;
    const int nblk = (N + 63) / 64;
    int CAP = ((E / (NB > 0 ? NB : 1)) * 3 / 2 + 255) & ~255;
    if (CAP < 1024) CAP = 1024;
    const size_t NC = (size_t)NB * CAP;

    // ws layout (ints): off[N] deg[N] | ed[2NC] | bcur[NB] | edw[2NC] | dlu[NC/2 ints] | featb[64N] h1b[64N] h2b[64N]
    const size_t o_off = 0;
    const size_t o_deg = (size_t)N;
    const size_t o_ed  = ((size_t)2 * N + 3) & ~(size_t)3;
    const size_t o_bc  = o_ed + 2 * NC;
    const size_t o_un  = (o_bc + NB + 3) & ~(size_t)3;
    const size_t o_dl  = o_un + 2 * NC;
    const size_t o_fb  = (o_dl + (NC + 1) / 2 + 3) & ~(size_t)3;
    const size_t need  = (o_fb + 3 * (size_t)64 * N) * 4;

    if (NB <= NBMAX && ws_size >= need) {
        int* ws_i  = (int*)d_ws;
        int* off   = ws_i + o_off;
        int* deg   = ws_i + o_deg;
        int2* ed   = (int2*)(ws_i + o_ed);
        int* bcur  = ws_i + o_bc;
        int2* edw  = (int2*)(ws_i + o_un);
        unsigned short* dlu = (unsigned short*)(ws_i + o_dl);
        unsigned short* featb = (unsigned short*)(ws_i + o_fb);
        unsigned short* h1b   = featb + (size_t)N * 128;
        unsigned short* h2b   = h1b + (size_t)N * 128;

        hipMemsetAsync(bcur, 0, (size_t)NB * 4, stream);
        multisplit_pack_kernel<<<(E + CH - 1) / CH, 256, 0, stream>>>(
            src, dst, w, bcur, edw, dlu, E, CAP, features, featb, (long)N * 32);
        bucket_csr_kernel<<<NB, 256, 0, stream>>>(edw, dlu, bcur, off, deg, ed, N, CAP);

        gather_wave<<<(N + 3) / 4, 256, 0, stream>>>(featb, off, deg, ed, Dn, h1b, N);
        gather_wave<<<(N + 3) / 4, 256, 0, stream>>>(h1b, off, deg, ed, Dn, h2b, N);

        dim3 tg((N + 127) / 128, 3);
        transform3_kernel<<<tg, 256, 0, stream>>>(featb, h1b, h2b, W, b, scale, offset, out, N);
    } else {
        // fallback: atomic scatter path (raw agg stored; Dn applied on read)
        hipMemsetAsync(out, 0, (size_t)out_size * sizeof(float), stream);
        scatter_kernel<<<2048, 256, 0, stream>>>(features, 128, 0, src, dst, w, Dn, 0, out, 128, E);
        scatter_kernel<<<2048, 256, 0, stream>>>(out, OUT_STRIDE, 128, src, dst, w, Dn, 1, out, 256, E);
        transform_f32_kernel<<<nblk, 256, 0, stream>>>(features, 128, 0, Dn, W, b, scale, offset, out, 0, N);
        transform_f32_kernel<<<nblk, 256, 0, stream>>>(out + 128, OUT_STRIDE, 1, Dn, W + 128 * 128, b + 128, scale + 128, offset + 128, out, 128, N);
        transform_f32_kernel<<<nblk, 256, 0, stream>>>(out + 256, OUT_STRIDE, 1, Dn, W + 2 * 128 * 128, b + 256, scale + 256, offset + 256, out, 256, N);
    }
}